// Round 8
// baseline (225.989 us; speedup 1.0000x reference)
//
#include <hip/hip_runtime.h>
#include <hip/hip_fp16.h>
#include <math.h>

#define CAP 64          // max incidences per node (mean deg = 8)
#define D1 128
#define D2 16
#define C_OUT 40
#define K_EDGE 32
#define CLAMP_LO 1e-7f
#define CLAMP_HI 10.0f
#define SQRT_INV31 0.1796053020267749f   // sqrt(1/31)

typedef unsigned short ushort_t;
typedef _Float16 h2v __attribute__((ext_vector_type(2)));   // packed fp16 pair

// Pure-streaming setup: clip+square -> Hp (fp16), W1 transpose, zero rows of
// S/S2. Incidence build lives in k_edge_sum (r7: -25us vs isolated build).
__global__ __launch_bounds__(256) void k_setup(const float* __restrict__ x,
                                               __half2* __restrict__ Hp,
                                               const float* __restrict__ W1,
                                               float* __restrict__ W1t,
                                               __half2* __restrict__ S,
                                               float* __restrict__ S2,
                                               int n4, int E) {
    int i = blockIdx.x * 256 + threadIdx.x;
    if (i < n4) {                                  // clip + square, 4 floats
        float4 v = ((const float4*)x)[i];
        v.x = fminf(fmaxf(v.x, CLAMP_LO), CLAMP_HI);
        v.y = fminf(fmaxf(v.y, CLAMP_LO), CLAMP_HI);
        v.z = fminf(fmaxf(v.z, CLAMP_LO), CLAMP_HI);
        v.w = fminf(fmaxf(v.w, CLAMP_LO), CLAMP_HI);
        Hp[2 * i]     = __floats2half2_rn(v.x * v.x, v.y * v.y);
        Hp[2 * i + 1] = __floats2half2_rn(v.z * v.z, v.w * v.w);
    }
    if (i < D1 * D2) W1t[(i & 15) * D1 + (i >> 4)] = W1[i];
    if (i < 64) S[(size_t)E * 64 + i] = __floats2half2_rn(0.0f, 0.0f);
    if (i < D2) S2[(size_t)E * D2 + i] = 0.0f;
}

// S[e,:] = sum of Hp[node,:] over the edge's 32 nodes + fused incidence
// build. FOUR edges per wave with the 64-lane-row structure kept (r3 showed
// 16-lane rows regress): two coalesced 64-id loads, 4 independent gathers
// per j-iteration (2x in-flight vs r7), 8 independent accumulator chains,
// 2 atomics/lane for the build. Grid = E/16 blocks ~ 6.1/CU -> one
// residency round (was 12/CU -> two rounds + tail).
__global__ __launch_bounds__(256) void k_edge_sum(const __half2* __restrict__ Hp,
                                                  const int* __restrict__ idx,
                                                  __half2* __restrict__ S,
                                                  int* __restrict__ deg,
                                                  ushort_t* __restrict__ lst, int E) {
    int w = threadIdx.x >> 6;
    int lane = threadIdx.x & 63;
    int eA = blockIdx.x * 16 + w * 4;           // 4 edges per wave; E % 4 == 0
    if (eA >= E) return;
    int nid0 = idx[eA * K_EDGE + lane];         // ids of edges eA, eA+1
    int nid1 = idx[(eA + 2) * K_EDGE + lane];   // ids of edges eA+2, eA+3
    float a0 = 0.0f, a1 = 0.0f, b0 = 0.0f, b1 = 0.0f;
    float c0 = 0.0f, c1 = 0.0f, d0 = 0.0f, d1 = 0.0f;
#pragma unroll
    for (int j = 0; j < K_EDGE; j++) {
        int nA = __builtin_amdgcn_readlane(nid0, j);
        int nB = __builtin_amdgcn_readlane(nid0, 32 + j);
        int nC = __builtin_amdgcn_readlane(nid1, j);
        int nD = __builtin_amdgcn_readlane(nid1, 32 + j);
        __half2 hA = Hp[(size_t)nA * 64 + lane];
        __half2 hB = Hp[(size_t)nB * 64 + lane];
        __half2 hC = Hp[(size_t)nC * 64 + lane];
        __half2 hD = Hp[(size_t)nD * 64 + lane];
        a0 += __low2float(hA); a1 += __high2float(hA);
        b0 += __low2float(hB); b1 += __high2float(hB);
        c0 += __low2float(hC); c1 += __high2float(hC);
        d0 += __low2float(hD); d1 += __high2float(hD);
    }
    // incidence build for the 128 incidences this wave already loaded
    int half = lane >> 5;
    int pos0 = atomicAdd(&deg[nid0], 1);
    if (pos0 < CAP) lst[(size_t)nid0 * CAP + pos0] = (ushort_t)(eA + half);
    int pos1 = atomicAdd(&deg[nid1], 1);
    if (pos1 < CAP) lst[(size_t)nid1 * CAP + pos1] = (ushort_t)(eA + 2 + half);

    S[(size_t)eA * 64 + lane]       = __floats2half2_rn(a0, a1);
    S[(size_t)(eA + 1) * 64 + lane] = __floats2half2_rn(b0, b1);
    S[(size_t)(eA + 2) * 64 + lane] = __floats2half2_rn(c0, c1);
    S[(size_t)(eA + 3) * 64 + lane] = __floats2half2_rn(d0, d1);
}

// Fused layer-1 node kernel. FOUR nodes per wave: lane -> (g=lane>>4 node,
// sl=lane&15 slot) so the lst load is one fully-coalesced 64-lane load and
// 48 gathers (4 nodes x 12 slots) are in flight per wave (2x MLP vs 2-node).
// Zero-row padding: unused slots carry edge id E (row E of S is zeros).
// Compute degree-gated on wave-uniform max-degree: slots 0-7 always,
// 8-11 if dmax>8 (~91%), 12-15 load+compute if dmax>12 (~40%).
__global__ __launch_bounds__(256) void k_node1(const __half2* __restrict__ Hp,
                                               const __half2* __restrict__ S,
                                               const int* __restrict__ deg,
                                               const ushort_t* __restrict__ lst,
                                               const float* __restrict__ W1t,
                                               const float* __restrict__ b1,
                                               float* __restrict__ Hp2, int N, int E) {
    int w = threadIdx.x >> 6;
    int lane = threadIdx.x & 63;
    int quad = blockIdx.x * 4 + w;              // wave handles nodes 4q..4q+3
    int n0 = quad * 4;                          // N % 16 == 0
    int c = lane & 15, j = lane >> 4;
    int sl = lane & 15, g = lane >> 4;

    int4 d4 = ((const int4*)deg)[quad];
    int dgA = min(d4.x, CAP), dgB = min(d4.y, CAP);
    int dgC = min(d4.z, CAP), dgD = min(d4.w, CAP);

    // coalesced: lane g*16+sl loads slot sl of node n0+g
    ushort_t idu = lst[(n0 + g) * CAP + sl];
    int dsel = (g == 0) ? dgA : (g == 1) ? dgB : (g == 2) ? dgC : dgD;
    int e_sel = (sl < dsel) ? (int)idu : E;

    __half2 hphA = Hp[(size_t)(n0 + 0) * 64 + lane];
    __half2 hphB = Hp[(size_t)(n0 + 1) * 64 + lane];
    __half2 hphC = Hp[(size_t)(n0 + 2) * 64 + lane];
    __half2 hphD = Hp[(size_t)(n0 + 3) * 64 + lane];
    h2v hpA, hpB, hpC, hpD;
    __builtin_memcpy(&hpA, &hphA, 4);
    __builtin_memcpy(&hpB, &hphB, 4);
    __builtin_memcpy(&hpC, &hphC, 4);
    __builtin_memcpy(&hpD, &hphD, 4);
    const h2v zv = (h2v)(_Float16)0.0f;

    int dmax = max(max(dgA, dgB), max(dgC, dgD));
    int dmaxc = min(dmax, 16);

    float aA0 = 0.0f, aA1 = 0.0f, aB0 = 0.0f, aB1 = 0.0f;
    float aC0 = 0.0f, aC1 = 0.0f, aD0 = 0.0f, aD1 = 0.0f;

    // ---- unconditional prefetch: slots 0..11 x 4 nodes (48 gathers) ----
    h2v sA[12], sB[12], sC[12], sD[12];
#pragma unroll
    for (int t = 0; t < 12; t++) {
        int eA = __builtin_amdgcn_readlane(e_sel, t);
        int eB = __builtin_amdgcn_readlane(e_sel, 16 + t);
        int eC = __builtin_amdgcn_readlane(e_sel, 32 + t);
        int eD = __builtin_amdgcn_readlane(e_sel, 48 + t);
        __half2 hv;
        hv = S[(size_t)eA * 64 + lane]; __builtin_memcpy(&sA[t], &hv, 4);
        hv = S[(size_t)eB * 64 + lane]; __builtin_memcpy(&sB[t], &hv, 4);
        hv = S[(size_t)eC * 64 + lane]; __builtin_memcpy(&sC[t], &hv, 4);
        hv = S[(size_t)eD * 64 + lane]; __builtin_memcpy(&sD[t], &hv, 4);
    }

    // ---- compute slots 0..7 (covers deg <= 8) ----
#pragma unroll
    for (int t = 0; t < 8; t++) {
        h2v dA = __builtin_elementwise_max(sA[t] - hpA, zv);
        h2v dB = __builtin_elementwise_max(sB[t] - hpB, zv);
        h2v dC = __builtin_elementwise_max(sC[t] - hpC, zv);
        h2v dD = __builtin_elementwise_max(sD[t] - hpD, zv);
        aA0 += __builtin_amdgcn_sqrtf((float)dA[0]);
        aA1 += __builtin_amdgcn_sqrtf((float)dA[1]);
        aB0 += __builtin_amdgcn_sqrtf((float)dB[0]);
        aB1 += __builtin_amdgcn_sqrtf((float)dB[1]);
        aC0 += __builtin_amdgcn_sqrtf((float)dC[0]);
        aC1 += __builtin_amdgcn_sqrtf((float)dC[1]);
        aD0 += __builtin_amdgcn_sqrtf((float)dD[0]);
        aD1 += __builtin_amdgcn_sqrtf((float)dD[1]);
    }

    if (dmaxc > 8) {                            // slots 8..11 (~91% of waves)
#pragma unroll
        for (int t = 8; t < 12; t++) {
            h2v dA = __builtin_elementwise_max(sA[t] - hpA, zv);
            h2v dB = __builtin_elementwise_max(sB[t] - hpB, zv);
            h2v dC = __builtin_elementwise_max(sC[t] - hpC, zv);
            h2v dD = __builtin_elementwise_max(sD[t] - hpD, zv);
            aA0 += __builtin_amdgcn_sqrtf((float)dA[0]);
            aA1 += __builtin_amdgcn_sqrtf((float)dA[1]);
            aB0 += __builtin_amdgcn_sqrtf((float)dB[0]);
            aB1 += __builtin_amdgcn_sqrtf((float)dB[1]);
            aC0 += __builtin_amdgcn_sqrtf((float)dC[0]);
            aC1 += __builtin_amdgcn_sqrtf((float)dC[1]);
            aD0 += __builtin_amdgcn_sqrtf((float)dD[0]);
            aD1 += __builtin_amdgcn_sqrtf((float)dD[1]);
        }
        if (dmaxc > 12) {                       // slots 12..15 (~40% of waves)
#pragma unroll
            for (int t = 0; t < 4; t++) {
                int eA = __builtin_amdgcn_readlane(e_sel, 12 + t);
                int eB = __builtin_amdgcn_readlane(e_sel, 28 + t);
                int eC = __builtin_amdgcn_readlane(e_sel, 44 + t);
                int eD = __builtin_amdgcn_readlane(e_sel, 60 + t);
                __half2 hv;
                h2v uA, uB, uC, uD;
                hv = S[(size_t)eA * 64 + lane]; __builtin_memcpy(&uA, &hv, 4);
                hv = S[(size_t)eB * 64 + lane]; __builtin_memcpy(&uB, &hv, 4);
                hv = S[(size_t)eC * 64 + lane]; __builtin_memcpy(&uC, &hv, 4);
                hv = S[(size_t)eD * 64 + lane]; __builtin_memcpy(&uD, &hv, 4);
                h2v dA = __builtin_elementwise_max(uA - hpA, zv);
                h2v dB = __builtin_elementwise_max(uB - hpB, zv);
                h2v dC = __builtin_elementwise_max(uC - hpC, zv);
                h2v dD = __builtin_elementwise_max(uD - hpD, zv);
                aA0 += __builtin_amdgcn_sqrtf((float)dA[0]);
                aA1 += __builtin_amdgcn_sqrtf((float)dA[1]);
                aB0 += __builtin_amdgcn_sqrtf((float)dB[0]);
                aB1 += __builtin_amdgcn_sqrtf((float)dB[1]);
                aC0 += __builtin_amdgcn_sqrtf((float)dC[0]);
                aC1 += __builtin_amdgcn_sqrtf((float)dC[1]);
                aD0 += __builtin_amdgcn_sqrtf((float)dD[0]);
                aD1 += __builtin_amdgcn_sqrtf((float)dD[1]);
            }
        }
    }

    // rare tails deg > 16 (P ~ 0.4%/node)
    if (dmax > 16) {
        float hA0 = (float)hpA[0], hA1 = (float)hpA[1];
        float hB0 = (float)hpB[0], hB1 = (float)hpB[1];
        float hC0 = (float)hpC[0], hC1 = (float)hpC[1];
        float hD0 = (float)hpD[0], hD1 = (float)hpD[1];
        for (int t = 16; t < dgA; t++) {
            int e = lst[(n0 + 0) * CAP + t];
            __half2 sh = S[(size_t)e * 64 + lane];
            aA0 += __builtin_amdgcn_sqrtf(fmaxf(__low2float(sh)  - hA0, 0.0f));
            aA1 += __builtin_amdgcn_sqrtf(fmaxf(__high2float(sh) - hA1, 0.0f));
        }
        for (int t = 16; t < dgB; t++) {
            int e = lst[(n0 + 1) * CAP + t];
            __half2 sh = S[(size_t)e * 64 + lane];
            aB0 += __builtin_amdgcn_sqrtf(fmaxf(__low2float(sh)  - hB0, 0.0f));
            aB1 += __builtin_amdgcn_sqrtf(fmaxf(__high2float(sh) - hB1, 0.0f));
        }
        for (int t = 16; t < dgC; t++) {
            int e = lst[(n0 + 2) * CAP + t];
            __half2 sh = S[(size_t)e * 64 + lane];
            aC0 += __builtin_amdgcn_sqrtf(fmaxf(__low2float(sh)  - hC0, 0.0f));
            aC1 += __builtin_amdgcn_sqrtf(fmaxf(__high2float(sh) - hC1, 0.0f));
        }
        for (int t = 16; t < dgD; t++) {
            int e = lst[(n0 + 3) * CAP + t];
            __half2 sh = S[(size_t)e * 64 + lane];
            aD0 += __builtin_amdgcn_sqrtf(fmaxf(__low2float(sh)  - hD0, 0.0f));
            aD1 += __builtin_amdgcn_sqrtf(fmaxf(__high2float(sh) - hD1, 0.0f));
        }
    }

    float nsA0 = __builtin_amdgcn_sqrtf((float)hpA[0]) + aA0 * SQRT_INV31;
    float nsA1 = __builtin_amdgcn_sqrtf((float)hpA[1]) + aA1 * SQRT_INV31;
    float nsB0 = __builtin_amdgcn_sqrtf((float)hpB[0]) + aB0 * SQRT_INV31;
    float nsB1 = __builtin_amdgcn_sqrtf((float)hpB[1]) + aB1 * SQRT_INV31;
    float nsC0 = __builtin_amdgcn_sqrtf((float)hpC[0]) + aC0 * SQRT_INV31;
    float nsC1 = __builtin_amdgcn_sqrtf((float)hpC[1]) + aC1 * SQRT_INV31;
    float nsD0 = __builtin_amdgcn_sqrtf((float)hpD[0]) + aD0 * SQRT_INV31;
    float nsD1 = __builtin_amdgcn_sqrtf((float)hpD[1]) + aD1 * SQRT_INV31;

    __shared__ float AHs[4][4][D1];             // wave-private [w][node][col]
    AHs[w][0][2 * lane] = nsA0;  AHs[w][0][2 * lane + 1] = nsA1;
    AHs[w][1][2 * lane] = nsB0;  AHs[w][1][2 * lane + 1] = nsB1;
    AHs[w][2][2 * lane] = nsC0;  AHs[w][2][2 * lane + 1] = nsC1;
    AHs[w][3][2 * lane] = nsD0;  AHs[w][3][2 * lane + 1] = nsD1;

    float vA = nsA0 + nsA1, vB = nsB0 + nsB1;
    float vC = nsC0 + nsC1, vD = nsD0 + nsD1;
#pragma unroll
    for (int m = 1; m < 64; m <<= 1) {
        vA += __shfl_xor(vA, m, 64);
        vB += __shfl_xor(vB, m, 64);
        vC += __shfl_xor(vC, m, 64);
        vD += __shfl_xor(vD, m, 64);
    }
    float rA = __builtin_amdgcn_rcpf(vA);
    float rB = __builtin_amdgcn_rcpf(vB);
    float rC = __builtin_amdgcn_rcpf(vC);
    float rD = __builtin_amdgcn_rcpf(vD);

    __threadfence_block();                      // LDS visibility within wave

    // ns[128] @ W1[128,16] for 4 nodes, sharing the W1t fragment.
    const float4* aAp = (const float4*)(&AHs[w][0][j * 32]);
    const float4* aBp = (const float4*)(&AHs[w][1][j * 32]);
    const float4* aCp = (const float4*)(&AHs[w][2][j * 32]);
    const float4* aDp = (const float4*)(&AHs[w][3][j * 32]);
    const float4* w1p = (const float4*)(W1t + c * D1 + j * 32);
    float pA = 0.0f, pB = 0.0f, pC = 0.0f, pD = 0.0f;
#pragma unroll
    for (int tt = 0; tt < 8; tt++) {
        float4 wv = w1p[tt];
        float4 xA = aAp[tt];
        float4 xB = aBp[tt];
        float4 xC = aCp[tt];
        float4 xD = aDp[tt];
        pA += xA.x * wv.x + xA.y * wv.y + xA.z * wv.z + xA.w * wv.w;
        pB += xB.x * wv.x + xB.y * wv.y + xB.z * wv.z + xB.w * wv.w;
        pC += xC.x * wv.x + xC.y * wv.y + xC.z * wv.z + xC.w * wv.w;
        pD += xD.x * wv.x + xD.y * wv.y + xD.z * wv.z + xD.w * wv.w;
    }
    pA += __shfl_xor(pA, 16, 64);  pA += __shfl_xor(pA, 32, 64);
    pB += __shfl_xor(pB, 16, 64);  pB += __shfl_xor(pB, 32, 64);
    pC += __shfl_xor(pC, 16, 64);  pC += __shfl_xor(pC, 32, 64);
    pD += __shfl_xor(pD, 16, 64);  pD += __shfl_xor(pD, 32, 64);

    float bb = b1[c];
    float oA = fminf(fmaxf(bb + pA * rA, CLAMP_LO), CLAMP_HI);
    float oB = fminf(fmaxf(bb + pB * rB, CLAMP_LO), CLAMP_HI);
    float oC = fminf(fmaxf(bb + pC * rC, CLAMP_LO), CLAMP_HI);
    float oD = fminf(fmaxf(bb + pD * rD, CLAMP_LO), CLAMP_HI);
    float qA = oA * oA, qB = oB * oB, qC = oC * oC, qD = oD * oD;
    // lane g*16+c stores node n0+g, col c  ->  Hp2 + 64*quad + lane (coalesced)
    float val = (g == 0) ? qA : (g == 1) ? qB : (g == 2) ? qC : qD;
    Hp2[(size_t)quad * 64 + lane] = val;
}

// S2[e,:] = sum over 32 nodes of Hp2[node,:] (d=16, fp32).
__global__ __launch_bounds__(256) void k_edge_sum2(const float* __restrict__ Hp2,
                                                   const int* __restrict__ idx,
                                                   float* __restrict__ S2, int E) {
    int e = blockIdx.x * 16 + (threadIdx.x >> 4);
    int col = threadIdx.x & 15;
    if (e >= E) return;
    float acc = 0.0f;
#pragma unroll
    for (int j = 0; j < K_EDGE; j++) {
        int n = idx[e * K_EDGE + j];
        acc += Hp2[(size_t)n * D2 + col];
    }
    S2[(size_t)e * D2 + col] = acc;
}

// Fused layer-2 node kernel. TWO nodes per wave: node = lane bit 5, two
// 16-lane subgroups per node split the 16 gather slots. uint16 lst.
// All 8 gathers per lane issued unconditionally (padding -> zero row);
// compute of slots 4..7 gated by max(dg0,dg1) > 8.
__global__ __launch_bounds__(256) void k_node2(const float* __restrict__ Hp2,
                                               const float* __restrict__ S2,
                                               const int* __restrict__ deg,
                                               const ushort_t* __restrict__ lst,
                                               const float* __restrict__ W2,
                                               const float* __restrict__ b2,
                                               float* __restrict__ out, int N, int E) {
    int w = threadIdx.x >> 6;
    int lane = threadIdx.x & 63;
    int pair = blockIdx.x * 4 + w;
    int n0 = pair * 2, n1 = n0 + 1;
    int col = lane & 15;
    int node = lane >> 5;                       // 0 or 1
    int gg = (lane >> 4) & 1;                   // subgroup within node
    int nn = node ? n1 : n0;

    int2 dg2 = ((const int2*)deg)[pair];
    int dg0 = min(dg2.x, CAP), dg1 = min(dg2.y, CAP);
    int sl = lane & 15;
    ushort_t idu = (lane < 32) ? lst[((lane < 16) ? n0 : n1) * CAP + sl] : (ushort_t)0;
    int dsel = (lane < 16) ? dg0 : dg1;
    int e_sel = (lane < 32 && sl < dsel) ? (int)idu : E;   // E = zero row of S2

    float hp = Hp2[(size_t)nn * D2 + col];
    int dgn = node ? dg1 : dg0;
    int dm = max(dg0, dg1);

    // unconditional: all 8 slots {2t+gg}, t=0..7 for this node's 16 slots
    int ev[8];
#pragma unroll
    for (int t = 0; t < 8; t++) ev[t] = __shfl(e_sel, node * 16 + 2 * t + gg, 64);
    float sv[8];
#pragma unroll
    for (int t = 0; t < 8; t++) sv[t] = S2[(size_t)ev[t] * D2 + col];

    float acc = 0.0f;
#pragma unroll
    for (int t = 0; t < 4; t++)
        acc += __builtin_amdgcn_sqrtf(fmaxf(sv[t] - hp, 0.0f));
    if (dm > 8) {
#pragma unroll
        for (int t = 4; t < 8; t++)
            acc += __builtin_amdgcn_sqrtf(fmaxf(sv[t] - hp, 0.0f));
    }
    for (int t = 16; t < dgn; t++) {            // rare tail; add once (gg==0)
        int e = lst[nn * CAP + t];
        float s = S2[(size_t)e * D2 + col];
        if (gg == 0) acc += __builtin_amdgcn_sqrtf(fmaxf(s - hp, 0.0f));
    }
    acc += __shfl_xor(acc, 16, 64);             // combine the node's 2 subgroups
    float ns = __builtin_amdgcn_sqrtf(hp) + acc * SQRT_INV31;

    float v = ns;
#pragma unroll
    for (int m = 1; m < 16; m <<= 1) v += __shfl_xor(v, m, 64);  // rowsum (16 cols)
    float r = __builtin_amdgcn_rcpf(v);

    __shared__ float AHs[4][2][D2];             // wave-private
    if (gg == 0) AHs[w][node][col] = ns * r;
    __threadfence_block();

    if (lane < C_OUT) {
        float o0 = b2[lane], o1 = o0;
#pragma unroll
        for (int i = 0; i < D2; i++) {
            float wv = W2[i * C_OUT + lane];
            o0 += AHs[w][0][i] * wv;
            o1 += AHs[w][1][i] * wv;
        }
        out[(size_t)n0 * C_OUT + lane] = o0;
        out[(size_t)n1 * C_OUT + lane] = o1;
    }
}

extern "C" void kernel_launch(void* const* d_in, const int* in_sizes, int n_in,
                              void* d_out, int out_size, void* d_ws, size_t ws_size,
                              hipStream_t stream) {
    const float* x   = (const float*)d_in[0];
    const int*   idx = (const int*)d_in[1];
    const float* W1  = (const float*)d_in[2];
    const float* b1  = (const float*)d_in[3];
    const float* W2  = (const float*)d_in[4];
    const float* b2  = (const float*)d_in[5];
    float* out = (float*)d_out;

    int N = in_sizes[0] / D1;     // 100000
    int E = in_sizes[1] / K_EDGE; // 25000

    // workspace layout (S and S2 have one extra zero row at index E)
    __half2* Hp = (__half2*)d_ws;                          // N*64 half2
    __half2* S  = Hp + (size_t)N * 64;                     // (E+1)*64 half2
    float* Hp2  = (float*)(S + (size_t)(E + 1) * 64);      // N*16 fp32
    float* S2   = Hp2 + (size_t)N * D2;                    // (E+1)*16 fp32
    float* W1t  = S2 + (size_t)(E + 1) * D2;               // 16*128 fp32
    int*   deg  = (int*)(W1t + D1 * D2);                   // N ints
    ushort_t* lst = (ushort_t*)(deg + N);                  // N*CAP uint16

    int n4 = N * D1 / 4;           // 3200000

    (void)hipMemsetAsync(deg, 0, (size_t)N * sizeof(int), stream);
    k_setup<<<(n4 + 255) / 256, 256, 0, stream>>>(x, Hp, W1, W1t, S, S2, n4, E);
    k_edge_sum<<<(E + 15) / 16, 256, 0, stream>>>(Hp, idx, S, deg, lst, E);
    k_node1<<<N / 16, 256, 0, stream>>>(Hp, S, deg, lst, W1t, b1, Hp2, N, E);
    k_edge_sum2<<<(E + 15) / 16, 256, 0, stream>>>(Hp2, idx, S2, E);
    k_node2<<<N / 8, 256, 0, stream>>>(Hp2, S2, deg, lst, W2, b2, out, N, E);
}

// Round 9
// 224.687 us; speedup vs baseline: 1.0058x; 1.0058x over previous
//
#include <hip/hip_runtime.h>
#include <hip/hip_fp16.h>
#include <math.h>

#define CAP 64          // max incidences per node (mean deg = 8)
#define D1 128
#define D2 16
#define C_OUT 40
#define K_EDGE 32
#define CLAMP_LO 1e-7f
#define CLAMP_HI 10.0f
#define SQRT_INV31 0.1796053020267749f   // sqrt(1/31)

typedef unsigned short ushort_t;
typedef _Float16 h2v __attribute__((ext_vector_type(2)));   // packed fp16 pair

// Pure-streaming setup: clip+square -> Hp (fp16), W1 transpose, zero rows of
// S/S2. Incidence build lives in k_edge_sum (r7: -25us vs isolated build).
__global__ __launch_bounds__(256) void k_setup(const float* __restrict__ x,
                                               __half2* __restrict__ Hp,
                                               const float* __restrict__ W1,
                                               float* __restrict__ W1t,
                                               __half2* __restrict__ S,
                                               float* __restrict__ S2,
                                               int n4, int E) {
    int i = blockIdx.x * 256 + threadIdx.x;
    if (i < n4) {                                  // clip + square, 4 floats
        float4 v = ((const float4*)x)[i];
        v.x = fminf(fmaxf(v.x, CLAMP_LO), CLAMP_HI);
        v.y = fminf(fmaxf(v.y, CLAMP_LO), CLAMP_HI);
        v.z = fminf(fmaxf(v.z, CLAMP_LO), CLAMP_HI);
        v.w = fminf(fmaxf(v.w, CLAMP_LO), CLAMP_HI);
        Hp[2 * i]     = __floats2half2_rn(v.x * v.x, v.y * v.y);
        Hp[2 * i + 1] = __floats2half2_rn(v.z * v.z, v.w * v.w);
    }
    if (i < D1 * D2) W1t[(i & 15) * D1 + (i >> 4)] = W1[i];
    if (i < 64) S[(size_t)E * 64 + i] = __floats2half2_rn(0.0f, 0.0f);
    if (i < D2) S2[(size_t)E * D2 + i] = 0.0f;
}

// S[e,:] = sum of Hp[node,:] over the edge's 32 nodes + fused incidence
// build (r7 2-edge version, restored: r8's 4-edge doubled VGPR 44->76,
// occupancy 39->23%, net -1.6us; kernel is L2-miss-latency bound and
// insensitive to per-wave MLP, so keep the higher-occupancy shape).
__global__ __launch_bounds__(256) void k_edge_sum(const __half2* __restrict__ Hp,
                                                  const int* __restrict__ idx,
                                                  __half2* __restrict__ S,
                                                  int* __restrict__ deg,
                                                  ushort_t* __restrict__ lst, int E) {
    int w = threadIdx.x >> 6;
    int lane = threadIdx.x & 63;
    int eA = blockIdx.x * 8 + w * 2;            // E % 8 == 0
    int nid = idx[eA * K_EDGE + lane];          // 32 ids of eA + 32 ids of eA+1
    float a0 = 0.0f, a1 = 0.0f, b0 = 0.0f, b1 = 0.0f;
#pragma unroll
    for (int j = 0; j < K_EDGE; j++) {
        int nA = __builtin_amdgcn_readlane(nid, j);
        int nB = __builtin_amdgcn_readlane(nid, 32 + j);
        __half2 hA = Hp[(size_t)nA * 64 + lane];
        __half2 hB = Hp[(size_t)nB * 64 + lane];
        a0 += __low2float(hA); a1 += __high2float(hA);
        b0 += __low2float(hB); b1 += __high2float(hB);
    }
    // incidence build for the 64 incidences this wave already loaded
    int e_of = eA + (lane >> 5);                // lane<32 -> eA, else eA+1
    int pos = atomicAdd(&deg[nid], 1);
    if (pos < CAP) lst[(size_t)nid * CAP + pos] = (ushort_t)e_of;

    S[(size_t)eA * 64 + lane]       = __floats2half2_rn(a0, a1);
    S[(size_t)(eA + 1) * 64 + lane] = __floats2half2_rn(b0, b1);
}

// Fused layer-1 node kernel. FOUR nodes per wave; gathers for slots 0..11
// unconditional (latency-hidden; padding hits zero row E). Slot COMPUTE is
// gated per node-PAIR (AB / CD) on the pair max-degree instead of the quad
// max: E[slots/node] 13.2 -> 11.3 (~15% of slot-VALU removed; kernel is
// VALU-bound at 67% busy). Slots 12..15 load+compute per pair when needed.
__global__ __launch_bounds__(256) void k_node1(const __half2* __restrict__ Hp,
                                               const __half2* __restrict__ S,
                                               const int* __restrict__ deg,
                                               const ushort_t* __restrict__ lst,
                                               const float* __restrict__ W1t,
                                               const float* __restrict__ b1,
                                               float* __restrict__ Hp2, int N, int E) {
    int w = threadIdx.x >> 6;
    int lane = threadIdx.x & 63;
    int quad = blockIdx.x * 4 + w;              // wave handles nodes 4q..4q+3
    int n0 = quad * 4;                          // N % 16 == 0
    int c = lane & 15, j = lane >> 4;
    int sl = lane & 15, g = lane >> 4;

    int4 d4 = ((const int4*)deg)[quad];
    int dgA = min(d4.x, CAP), dgB = min(d4.y, CAP);
    int dgC = min(d4.z, CAP), dgD = min(d4.w, CAP);

    // coalesced: lane g*16+sl loads slot sl of node n0+g
    ushort_t idu = lst[(n0 + g) * CAP + sl];
    int dsel = (g == 0) ? dgA : (g == 1) ? dgB : (g == 2) ? dgC : dgD;
    int e_sel = (sl < dsel) ? (int)idu : E;

    __half2 hphA = Hp[(size_t)(n0 + 0) * 64 + lane];
    __half2 hphB = Hp[(size_t)(n0 + 1) * 64 + lane];
    __half2 hphC = Hp[(size_t)(n0 + 2) * 64 + lane];
    __half2 hphD = Hp[(size_t)(n0 + 3) * 64 + lane];
    h2v hpA, hpB, hpC, hpD;
    __builtin_memcpy(&hpA, &hphA, 4);
    __builtin_memcpy(&hpB, &hphB, 4);
    __builtin_memcpy(&hpC, &hphC, 4);
    __builtin_memcpy(&hpD, &hphD, 4);
    const h2v zv = (h2v)(_Float16)0.0f;

    int dmAB = max(dgA, dgB);
    int dmCD = max(dgC, dgD);
    int dmax = max(dmAB, dmCD);

    float aA0 = 0.0f, aA1 = 0.0f, aB0 = 0.0f, aB1 = 0.0f;
    float aC0 = 0.0f, aC1 = 0.0f, aD0 = 0.0f, aD1 = 0.0f;

    // ---- unconditional prefetch: slots 0..11 x 4 nodes (48 gathers) ----
    h2v sA[12], sB[12], sC[12], sD[12];
#pragma unroll
    for (int t = 0; t < 12; t++) {
        int eA = __builtin_amdgcn_readlane(e_sel, t);
        int eB = __builtin_amdgcn_readlane(e_sel, 16 + t);
        int eC = __builtin_amdgcn_readlane(e_sel, 32 + t);
        int eD = __builtin_amdgcn_readlane(e_sel, 48 + t);
        __half2 hv;
        hv = S[(size_t)eA * 64 + lane]; __builtin_memcpy(&sA[t], &hv, 4);
        hv = S[(size_t)eB * 64 + lane]; __builtin_memcpy(&sB[t], &hv, 4);
        hv = S[(size_t)eC * 64 + lane]; __builtin_memcpy(&sC[t], &hv, 4);
        hv = S[(size_t)eD * 64 + lane]; __builtin_memcpy(&sD[t], &hv, 4);
    }

    // ---- compute slots 0..7 (covers deg <= 8) ----
#pragma unroll
    for (int t = 0; t < 8; t++) {
        h2v dA = __builtin_elementwise_max(sA[t] - hpA, zv);
        h2v dB = __builtin_elementwise_max(sB[t] - hpB, zv);
        h2v dC = __builtin_elementwise_max(sC[t] - hpC, zv);
        h2v dD = __builtin_elementwise_max(sD[t] - hpD, zv);
        aA0 += __builtin_amdgcn_sqrtf((float)dA[0]);
        aA1 += __builtin_amdgcn_sqrtf((float)dA[1]);
        aB0 += __builtin_amdgcn_sqrtf((float)dB[0]);
        aB1 += __builtin_amdgcn_sqrtf((float)dB[1]);
        aC0 += __builtin_amdgcn_sqrtf((float)dC[0]);
        aC1 += __builtin_amdgcn_sqrtf((float)dC[1]);
        aD0 += __builtin_amdgcn_sqrtf((float)dD[0]);
        aD1 += __builtin_amdgcn_sqrtf((float)dD[1]);
    }

    // ---- pair AB: slots 8..11 (P~0.70), 12..15 (P~0.12) ----
    if (dmAB > 8) {
#pragma unroll
        for (int t = 8; t < 12; t++) {
            h2v dA = __builtin_elementwise_max(sA[t] - hpA, zv);
            h2v dB = __builtin_elementwise_max(sB[t] - hpB, zv);
            aA0 += __builtin_amdgcn_sqrtf((float)dA[0]);
            aA1 += __builtin_amdgcn_sqrtf((float)dA[1]);
            aB0 += __builtin_amdgcn_sqrtf((float)dB[0]);
            aB1 += __builtin_amdgcn_sqrtf((float)dB[1]);
        }
        if (dmAB > 12) {
#pragma unroll
            for (int t = 0; t < 4; t++) {
                int eA = __builtin_amdgcn_readlane(e_sel, 12 + t);
                int eB = __builtin_amdgcn_readlane(e_sel, 28 + t);
                __half2 hv;
                h2v uA, uB;
                hv = S[(size_t)eA * 64 + lane]; __builtin_memcpy(&uA, &hv, 4);
                hv = S[(size_t)eB * 64 + lane]; __builtin_memcpy(&uB, &hv, 4);
                h2v dA = __builtin_elementwise_max(uA - hpA, zv);
                h2v dB = __builtin_elementwise_max(uB - hpB, zv);
                aA0 += __builtin_amdgcn_sqrtf((float)dA[0]);
                aA1 += __builtin_amdgcn_sqrtf((float)dA[1]);
                aB0 += __builtin_amdgcn_sqrtf((float)dB[0]);
                aB1 += __builtin_amdgcn_sqrtf((float)dB[1]);
            }
        }
    }

    // ---- pair CD: slots 8..11, 12..15 ----
    if (dmCD > 8) {
#pragma unroll
        for (int t = 8; t < 12; t++) {
            h2v dC = __builtin_elementwise_max(sC[t] - hpC, zv);
            h2v dD = __builtin_elementwise_max(sD[t] - hpD, zv);
            aC0 += __builtin_amdgcn_sqrtf((float)dC[0]);
            aC1 += __builtin_amdgcn_sqrtf((float)dC[1]);
            aD0 += __builtin_amdgcn_sqrtf((float)dD[0]);
            aD1 += __builtin_amdgcn_sqrtf((float)dD[1]);
        }
        if (dmCD > 12) {
#pragma unroll
            for (int t = 0; t < 4; t++) {
                int eC = __builtin_amdgcn_readlane(e_sel, 44 + t);
                int eD = __builtin_amdgcn_readlane(e_sel, 60 + t);
                __half2 hv;
                h2v uC, uD;
                hv = S[(size_t)eC * 64 + lane]; __builtin_memcpy(&uC, &hv, 4);
                hv = S[(size_t)eD * 64 + lane]; __builtin_memcpy(&uD, &hv, 4);
                h2v dC = __builtin_elementwise_max(uC - hpC, zv);
                h2v dD = __builtin_elementwise_max(uD - hpD, zv);
                aC0 += __builtin_amdgcn_sqrtf((float)dC[0]);
                aC1 += __builtin_amdgcn_sqrtf((float)dC[1]);
                aD0 += __builtin_amdgcn_sqrtf((float)dD[0]);
                aD1 += __builtin_amdgcn_sqrtf((float)dD[1]);
            }
        }
    }

    // rare tails deg > 16 (P ~ 0.4%/node)
    if (dmax > 16) {
        float hA0 = (float)hpA[0], hA1 = (float)hpA[1];
        float hB0 = (float)hpB[0], hB1 = (float)hpB[1];
        float hC0 = (float)hpC[0], hC1 = (float)hpC[1];
        float hD0 = (float)hpD[0], hD1 = (float)hpD[1];
        for (int t = 16; t < dgA; t++) {
            int e = lst[(n0 + 0) * CAP + t];
            __half2 sh = S[(size_t)e * 64 + lane];
            aA0 += __builtin_amdgcn_sqrtf(fmaxf(__low2float(sh)  - hA0, 0.0f));
            aA1 += __builtin_amdgcn_sqrtf(fmaxf(__high2float(sh) - hA1, 0.0f));
        }
        for (int t = 16; t < dgB; t++) {
            int e = lst[(n0 + 1) * CAP + t];
            __half2 sh = S[(size_t)e * 64 + lane];
            aB0 += __builtin_amdgcn_sqrtf(fmaxf(__low2float(sh)  - hB0, 0.0f));
            aB1 += __builtin_amdgcn_sqrtf(fmaxf(__high2float(sh) - hB1, 0.0f));
        }
        for (int t = 16; t < dgC; t++) {
            int e = lst[(n0 + 2) * CAP + t];
            __half2 sh = S[(size_t)e * 64 + lane];
            aC0 += __builtin_amdgcn_sqrtf(fmaxf(__low2float(sh)  - hC0, 0.0f));
            aC1 += __builtin_amdgcn_sqrtf(fmaxf(__high2float(sh) - hC1, 0.0f));
        }
        for (int t = 16; t < dgD; t++) {
            int e = lst[(n0 + 3) * CAP + t];
            __half2 sh = S[(size_t)e * 64 + lane];
            aD0 += __builtin_amdgcn_sqrtf(fmaxf(__low2float(sh)  - hD0, 0.0f));
            aD1 += __builtin_amdgcn_sqrtf(fmaxf(__high2float(sh) - hD1, 0.0f));
        }
    }

    float nsA0 = __builtin_amdgcn_sqrtf((float)hpA[0]) + aA0 * SQRT_INV31;
    float nsA1 = __builtin_amdgcn_sqrtf((float)hpA[1]) + aA1 * SQRT_INV31;
    float nsB0 = __builtin_amdgcn_sqrtf((float)hpB[0]) + aB0 * SQRT_INV31;
    float nsB1 = __builtin_amdgcn_sqrtf((float)hpB[1]) + aB1 * SQRT_INV31;
    float nsC0 = __builtin_amdgcn_sqrtf((float)hpC[0]) + aC0 * SQRT_INV31;
    float nsC1 = __builtin_amdgcn_sqrtf((float)hpC[1]) + aC1 * SQRT_INV31;
    float nsD0 = __builtin_amdgcn_sqrtf((float)hpD[0]) + aD0 * SQRT_INV31;
    float nsD1 = __builtin_amdgcn_sqrtf((float)hpD[1]) + aD1 * SQRT_INV31;

    __shared__ float AHs[4][4][D1];             // wave-private [w][node][col]
    AHs[w][0][2 * lane] = nsA0;  AHs[w][0][2 * lane + 1] = nsA1;
    AHs[w][1][2 * lane] = nsB0;  AHs[w][1][2 * lane + 1] = nsB1;
    AHs[w][2][2 * lane] = nsC0;  AHs[w][2][2 * lane + 1] = nsC1;
    AHs[w][3][2 * lane] = nsD0;  AHs[w][3][2 * lane + 1] = nsD1;

    float vA = nsA0 + nsA1, vB = nsB0 + nsB1;
    float vC = nsC0 + nsC1, vD = nsD0 + nsD1;
#pragma unroll
    for (int m = 1; m < 64; m <<= 1) {
        vA += __shfl_xor(vA, m, 64);
        vB += __shfl_xor(vB, m, 64);
        vC += __shfl_xor(vC, m, 64);
        vD += __shfl_xor(vD, m, 64);
    }
    float rA = __builtin_amdgcn_rcpf(vA);
    float rB = __builtin_amdgcn_rcpf(vB);
    float rC = __builtin_amdgcn_rcpf(vC);
    float rD = __builtin_amdgcn_rcpf(vD);

    __threadfence_block();                      // LDS visibility within wave

    // ns[128] @ W1[128,16] for 4 nodes, sharing the W1t fragment.
    const float4* aAp = (const float4*)(&AHs[w][0][j * 32]);
    const float4* aBp = (const float4*)(&AHs[w][1][j * 32]);
    const float4* aCp = (const float4*)(&AHs[w][2][j * 32]);
    const float4* aDp = (const float4*)(&AHs[w][3][j * 32]);
    const float4* w1p = (const float4*)(W1t + c * D1 + j * 32);
    float pA = 0.0f, pB = 0.0f, pC = 0.0f, pD = 0.0f;
#pragma unroll
    for (int tt = 0; tt < 8; tt++) {
        float4 wv = w1p[tt];
        float4 xA = aAp[tt];
        float4 xB = aBp[tt];
        float4 xC = aCp[tt];
        float4 xD = aDp[tt];
        pA += xA.x * wv.x + xA.y * wv.y + xA.z * wv.z + xA.w * wv.w;
        pB += xB.x * wv.x + xB.y * wv.y + xB.z * wv.z + xB.w * wv.w;
        pC += xC.x * wv.x + xC.y * wv.y + xC.z * wv.z + xC.w * wv.w;
        pD += xD.x * wv.x + xD.y * wv.y + xD.z * wv.z + xD.w * wv.w;
    }
    pA += __shfl_xor(pA, 16, 64);  pA += __shfl_xor(pA, 32, 64);
    pB += __shfl_xor(pB, 16, 64);  pB += __shfl_xor(pB, 32, 64);
    pC += __shfl_xor(pC, 16, 64);  pC += __shfl_xor(pC, 32, 64);
    pD += __shfl_xor(pD, 16, 64);  pD += __shfl_xor(pD, 32, 64);

    float bb = b1[c];
    float oA = fminf(fmaxf(bb + pA * rA, CLAMP_LO), CLAMP_HI);
    float oB = fminf(fmaxf(bb + pB * rB, CLAMP_LO), CLAMP_HI);
    float oC = fminf(fmaxf(bb + pC * rC, CLAMP_LO), CLAMP_HI);
    float oD = fminf(fmaxf(bb + pD * rD, CLAMP_LO), CLAMP_HI);
    float qA = oA * oA, qB = oB * oB, qC = oC * oC, qD = oD * oD;
    // lane g*16+c stores node n0+g, col c  ->  Hp2 + 64*quad + lane (coalesced)
    float val = (g == 0) ? qA : (g == 1) ? qB : (g == 2) ? qC : qD;
    Hp2[(size_t)quad * 64 + lane] = val;
}

// S2[e,:] = sum over 32 nodes of Hp2[node,:] (d=16, fp32).
__global__ __launch_bounds__(256) void k_edge_sum2(const float* __restrict__ Hp2,
                                                   const int* __restrict__ idx,
                                                   float* __restrict__ S2, int E) {
    int e = blockIdx.x * 16 + (threadIdx.x >> 4);
    int col = threadIdx.x & 15;
    if (e >= E) return;
    float acc = 0.0f;
#pragma unroll
    for (int j = 0; j < K_EDGE; j++) {
        int n = idx[e * K_EDGE + j];
        acc += Hp2[(size_t)n * D2 + col];
    }
    S2[(size_t)e * D2 + col] = acc;
}

// Fused layer-2 node kernel. TWO nodes per wave: node = lane bit 5, two
// 16-lane subgroups per node split the 16 gather slots. uint16 lst.
// All 8 gathers per lane issued unconditionally (padding -> zero row);
// compute of slots 4..7 gated by max(dg0,dg1) > 8.
__global__ __launch_bounds__(256) void k_node2(const float* __restrict__ Hp2,
                                               const float* __restrict__ S2,
                                               const int* __restrict__ deg,
                                               const ushort_t* __restrict__ lst,
                                               const float* __restrict__ W2,
                                               const float* __restrict__ b2,
                                               float* __restrict__ out, int N, int E) {
    int w = threadIdx.x >> 6;
    int lane = threadIdx.x & 63;
    int pair = blockIdx.x * 4 + w;
    int n0 = pair * 2, n1 = n0 + 1;
    int col = lane & 15;
    int node = lane >> 5;                       // 0 or 1
    int gg = (lane >> 4) & 1;                   // subgroup within node
    int nn = node ? n1 : n0;

    int2 dg2 = ((const int2*)deg)[pair];
    int dg0 = min(dg2.x, CAP), dg1 = min(dg2.y, CAP);
    int sl = lane & 15;
    ushort_t idu = (lane < 32) ? lst[((lane < 16) ? n0 : n1) * CAP + sl] : (ushort_t)0;
    int dsel = (lane < 16) ? dg0 : dg1;
    int e_sel = (lane < 32 && sl < dsel) ? (int)idu : E;   // E = zero row of S2

    float hp = Hp2[(size_t)nn * D2 + col];
    int dgn = node ? dg1 : dg0;
    int dm = max(dg0, dg1);

    // unconditional: all 8 slots {2t+gg}, t=0..7 for this node's 16 slots
    int ev[8];
#pragma unroll
    for (int t = 0; t < 8; t++) ev[t] = __shfl(e_sel, node * 16 + 2 * t + gg, 64);
    float sv[8];
#pragma unroll
    for (int t = 0; t < 8; t++) sv[t] = S2[(size_t)ev[t] * D2 + col];

    float acc = 0.0f;
#pragma unroll
    for (int t = 0; t < 4; t++)
        acc += __builtin_amdgcn_sqrtf(fmaxf(sv[t] - hp, 0.0f));
    if (dm > 8) {
#pragma unroll
        for (int t = 4; t < 8; t++)
            acc += __builtin_amdgcn_sqrtf(fmaxf(sv[t] - hp, 0.0f));
    }
    for (int t = 16; t < dgn; t++) {            // rare tail; add once (gg==0)
        int e = lst[nn * CAP + t];
        float s = S2[(size_t)e * D2 + col];
        if (gg == 0) acc += __builtin_amdgcn_sqrtf(fmaxf(s - hp, 0.0f));
    }
    acc += __shfl_xor(acc, 16, 64);             // combine the node's 2 subgroups
    float ns = __builtin_amdgcn_sqrtf(hp) + acc * SQRT_INV31;

    float v = ns;
#pragma unroll
    for (int m = 1; m < 16; m <<= 1) v += __shfl_xor(v, m, 64);  // rowsum (16 cols)
    float r = __builtin_amdgcn_rcpf(v);

    __shared__ float AHs[4][2][D2];             // wave-private
    if (gg == 0) AHs[w][node][col] = ns * r;
    __threadfence_block();

    if (lane < C_OUT) {
        float o0 = b2[lane], o1 = o0;
#pragma unroll
        for (int i = 0; i < D2; i++) {
            float wv = W2[i * C_OUT + lane];
            o0 += AHs[w][0][i] * wv;
            o1 += AHs[w][1][i] * wv;
        }
        out[(size_t)n0 * C_OUT + lane] = o0;
        out[(size_t)n1 * C_OUT + lane] = o1;
    }
}

extern "C" void kernel_launch(void* const* d_in, const int* in_sizes, int n_in,
                              void* d_out, int out_size, void* d_ws, size_t ws_size,
                              hipStream_t stream) {
    const float* x   = (const float*)d_in[0];
    const int*   idx = (const int*)d_in[1];
    const float* W1  = (const float*)d_in[2];
    const float* b1  = (const float*)d_in[3];
    const float* W2  = (const float*)d_in[4];
    const float* b2  = (const float*)d_in[5];
    float* out = (float*)d_out;

    int N = in_sizes[0] / D1;     // 100000
    int E = in_sizes[1] / K_EDGE; // 25000

    // workspace layout (S and S2 have one extra zero row at index E)
    __half2* Hp = (__half2*)d_ws;                          // N*64 half2
    __half2* S  = Hp + (size_t)N * 64;                     // (E+1)*64 half2
    float* Hp2  = (float*)(S + (size_t)(E + 1) * 64);      // N*16 fp32
    float* S2   = Hp2 + (size_t)N * D2;                    // (E+1)*16 fp32
    float* W1t  = S2 + (size_t)(E + 1) * D2;               // 16*128 fp32
    int*   deg  = (int*)(W1t + D1 * D2);                   // N ints
    ushort_t* lst = (ushort_t*)(deg + N);                  // N*CAP uint16

    int n4 = N * D1 / 4;           // 3200000

    (void)hipMemsetAsync(deg, 0, (size_t)N * sizeof(int), stream);
    k_setup<<<(n4 + 255) / 256, 256, 0, stream>>>(x, Hp, W1, W1t, S, S2, n4, E);
    k_edge_sum<<<E / 8, 256, 0, stream>>>(Hp, idx, S, deg, lst, E);
    k_node1<<<N / 16, 256, 0, stream>>>(Hp, S, deg, lst, W1t, b1, Hp2, N, E);
    k_edge_sum2<<<(E + 15) / 16, 256, 0, stream>>>(Hp2, idx, S2, E);
    k_node2<<<N / 8, 256, 0, stream>>>(Hp2, S2, deg, lst, W2, b2, out, N, E);
}

// Round 10
// 218.984 us; speedup vs baseline: 1.0320x; 1.0260x over previous
//
#include <hip/hip_runtime.h>
#include <hip/hip_fp16.h>
#include <math.h>

#define CAP 64          // max incidences per node (mean deg = 8)
#define D1 128
#define D2 16
#define C_OUT 40
#define K_EDGE 32
#define CLAMP_LO 1e-7f
#define CLAMP_HI 10.0f
#define SQRT_INV31 0.1796053020267749f   // sqrt(1/31)

typedef unsigned short ushort_t;
typedef _Float16 h2v __attribute__((ext_vector_type(2)));   // packed fp16 pair

// Pure-streaming setup: clip+square -> Hp (fp16), W1 transpose, zero rows of
// S/S2. Incidence build lives in k_edge_sum (r7: -25us vs isolated build).
__global__ __launch_bounds__(256) void k_setup(const float* __restrict__ x,
                                               __half2* __restrict__ Hp,
                                               const float* __restrict__ W1,
                                               float* __restrict__ W1t,
                                               __half2* __restrict__ S,
                                               float* __restrict__ S2,
                                               int n4, int E) {
    int i = blockIdx.x * 256 + threadIdx.x;
    if (i < n4) {                                  // clip + square, 4 floats
        float4 v = ((const float4*)x)[i];
        v.x = fminf(fmaxf(v.x, CLAMP_LO), CLAMP_HI);
        v.y = fminf(fmaxf(v.y, CLAMP_LO), CLAMP_HI);
        v.z = fminf(fmaxf(v.z, CLAMP_LO), CLAMP_HI);
        v.w = fminf(fmaxf(v.w, CLAMP_LO), CLAMP_HI);
        __half2 h0 = __floats2half2_rn(v.x * v.x, v.y * v.y);
        __half2 h1 = __floats2half2_rn(v.z * v.z, v.w * v.w);
        uint2 st;
        __builtin_memcpy(&st.x, &h0, 4);
        __builtin_memcpy(&st.y, &h1, 4);
        ((uint2*)Hp)[i] = st;                      // one 8B store (was 2x4B)
    }
    if (i < D1 * D2) W1t[(i & 15) * D1 + (i >> 4)] = W1[i];
    if (i < 64) S[(size_t)E * 64 + i] = __floats2half2_rn(0.0f, 0.0f);
    if (i < D2) S2[(size_t)E * D2 + i] = 0.0f;
}

// S[e,:] = sum of Hp[node,:] over the edge's 32 nodes + fused incidence
// build (r7 2-edge version; r8 showed the kernel is L2-path-throughput
// bound (~3 TB/s combined, FETCH 92MB = XCD-duplicated Hp, WRITE 55MB =
// lst 2B-scatter line RMW) and insensitive to per-wave MLP. Left alone.
__global__ __launch_bounds__(256) void k_edge_sum(const __half2* __restrict__ Hp,
                                                  const int* __restrict__ idx,
                                                  __half2* __restrict__ S,
                                                  int* __restrict__ deg,
                                                  ushort_t* __restrict__ lst, int E) {
    int w = threadIdx.x >> 6;
    int lane = threadIdx.x & 63;
    int eA = blockIdx.x * 8 + w * 2;            // E % 8 == 0
    int nid = idx[eA * K_EDGE + lane];          // 32 ids of eA + 32 ids of eA+1
    float a0 = 0.0f, a1 = 0.0f, b0 = 0.0f, b1 = 0.0f;
#pragma unroll
    for (int j = 0; j < K_EDGE; j++) {
        int nA = __builtin_amdgcn_readlane(nid, j);
        int nB = __builtin_amdgcn_readlane(nid, 32 + j);
        __half2 hA = Hp[(size_t)nA * 64 + lane];
        __half2 hB = Hp[(size_t)nB * 64 + lane];
        a0 += __low2float(hA); a1 += __high2float(hA);
        b0 += __low2float(hB); b1 += __high2float(hB);
    }
    // incidence build for the 64 incidences this wave already loaded
    int e_of = eA + (lane >> 5);                // lane<32 -> eA, else eA+1
    int pos = atomicAdd(&deg[nid], 1);
    if (pos < CAP) lst[(size_t)nid * CAP + pos] = (ushort_t)e_of;

    S[(size_t)eA * 64 + lane]       = __floats2half2_rn(a0, a1);
    S[(size_t)(eA + 1) * 64 + lane] = __floats2half2_rn(b0, b1);
}

// Fused layer-1 node kernel. FOUR nodes per wave; gathers for slots 0..11
// unconditional (latency-hidden; padding hits zero row E). Slot COMPUTE is
// gated per node-PAIR (AB / CD) on the pair max-degree (r9: node1 dropped
// below the top-5). Slots 12..15 load+compute per pair when needed.
__global__ __launch_bounds__(256) void k_node1(const __half2* __restrict__ Hp,
                                               const __half2* __restrict__ S,
                                               const int* __restrict__ deg,
                                               const ushort_t* __restrict__ lst,
                                               const float* __restrict__ W1t,
                                               const float* __restrict__ b1,
                                               float* __restrict__ Hp2, int N, int E) {
    int w = threadIdx.x >> 6;
    int lane = threadIdx.x & 63;
    int quad = blockIdx.x * 4 + w;              // wave handles nodes 4q..4q+3
    int n0 = quad * 4;                          // N % 16 == 0
    int c = lane & 15, j = lane >> 4;
    int sl = lane & 15, g = lane >> 4;

    int4 d4 = ((const int4*)deg)[quad];
    int dgA = min(d4.x, CAP), dgB = min(d4.y, CAP);
    int dgC = min(d4.z, CAP), dgD = min(d4.w, CAP);

    // coalesced: lane g*16+sl loads slot sl of node n0+g
    ushort_t idu = lst[(n0 + g) * CAP + sl];
    int dsel = (g == 0) ? dgA : (g == 1) ? dgB : (g == 2) ? dgC : dgD;
    int e_sel = (sl < dsel) ? (int)idu : E;

    __half2 hphA = Hp[(size_t)(n0 + 0) * 64 + lane];
    __half2 hphB = Hp[(size_t)(n0 + 1) * 64 + lane];
    __half2 hphC = Hp[(size_t)(n0 + 2) * 64 + lane];
    __half2 hphD = Hp[(size_t)(n0 + 3) * 64 + lane];
    h2v hpA, hpB, hpC, hpD;
    __builtin_memcpy(&hpA, &hphA, 4);
    __builtin_memcpy(&hpB, &hphB, 4);
    __builtin_memcpy(&hpC, &hphC, 4);
    __builtin_memcpy(&hpD, &hphD, 4);
    const h2v zv = (h2v)(_Float16)0.0f;

    int dmAB = max(dgA, dgB);
    int dmCD = max(dgC, dgD);
    int dmax = max(dmAB, dmCD);

    float aA0 = 0.0f, aA1 = 0.0f, aB0 = 0.0f, aB1 = 0.0f;
    float aC0 = 0.0f, aC1 = 0.0f, aD0 = 0.0f, aD1 = 0.0f;

    // ---- unconditional prefetch: slots 0..11 x 4 nodes (48 gathers) ----
    h2v sA[12], sB[12], sC[12], sD[12];
#pragma unroll
    for (int t = 0; t < 12; t++) {
        int eA = __builtin_amdgcn_readlane(e_sel, t);
        int eB = __builtin_amdgcn_readlane(e_sel, 16 + t);
        int eC = __builtin_amdgcn_readlane(e_sel, 32 + t);
        int eD = __builtin_amdgcn_readlane(e_sel, 48 + t);
        __half2 hv;
        hv = S[(size_t)eA * 64 + lane]; __builtin_memcpy(&sA[t], &hv, 4);
        hv = S[(size_t)eB * 64 + lane]; __builtin_memcpy(&sB[t], &hv, 4);
        hv = S[(size_t)eC * 64 + lane]; __builtin_memcpy(&sC[t], &hv, 4);
        hv = S[(size_t)eD * 64 + lane]; __builtin_memcpy(&sD[t], &hv, 4);
    }

    // ---- compute slots 0..7 (covers deg <= 8) ----
#pragma unroll
    for (int t = 0; t < 8; t++) {
        h2v dA = __builtin_elementwise_max(sA[t] - hpA, zv);
        h2v dB = __builtin_elementwise_max(sB[t] - hpB, zv);
        h2v dC = __builtin_elementwise_max(sC[t] - hpC, zv);
        h2v dD = __builtin_elementwise_max(sD[t] - hpD, zv);
        aA0 += __builtin_amdgcn_sqrtf((float)dA[0]);
        aA1 += __builtin_amdgcn_sqrtf((float)dA[1]);
        aB0 += __builtin_amdgcn_sqrtf((float)dB[0]);
        aB1 += __builtin_amdgcn_sqrtf((float)dB[1]);
        aC0 += __builtin_amdgcn_sqrtf((float)dC[0]);
        aC1 += __builtin_amdgcn_sqrtf((float)dC[1]);
        aD0 += __builtin_amdgcn_sqrtf((float)dD[0]);
        aD1 += __builtin_amdgcn_sqrtf((float)dD[1]);
    }

    // ---- pair AB: slots 8..11 (P~0.70), 12..15 (P~0.12) ----
    if (dmAB > 8) {
#pragma unroll
        for (int t = 8; t < 12; t++) {
            h2v dA = __builtin_elementwise_max(sA[t] - hpA, zv);
            h2v dB = __builtin_elementwise_max(sB[t] - hpB, zv);
            aA0 += __builtin_amdgcn_sqrtf((float)dA[0]);
            aA1 += __builtin_amdgcn_sqrtf((float)dA[1]);
            aB0 += __builtin_amdgcn_sqrtf((float)dB[0]);
            aB1 += __builtin_amdgcn_sqrtf((float)dB[1]);
        }
        if (dmAB > 12) {
#pragma unroll
            for (int t = 0; t < 4; t++) {
                int eA = __builtin_amdgcn_readlane(e_sel, 12 + t);
                int eB = __builtin_amdgcn_readlane(e_sel, 28 + t);
                __half2 hv;
                h2v uA, uB;
                hv = S[(size_t)eA * 64 + lane]; __builtin_memcpy(&uA, &hv, 4);
                hv = S[(size_t)eB * 64 + lane]; __builtin_memcpy(&uB, &hv, 4);
                h2v dA = __builtin_elementwise_max(uA - hpA, zv);
                h2v dB = __builtin_elementwise_max(uB - hpB, zv);
                aA0 += __builtin_amdgcn_sqrtf((float)dA[0]);
                aA1 += __builtin_amdgcn_sqrtf((float)dA[1]);
                aB0 += __builtin_amdgcn_sqrtf((float)dB[0]);
                aB1 += __builtin_amdgcn_sqrtf((float)dB[1]);
            }
        }
    }

    // ---- pair CD: slots 8..11, 12..15 ----
    if (dmCD > 8) {
#pragma unroll
        for (int t = 8; t < 12; t++) {
            h2v dC = __builtin_elementwise_max(sC[t] - hpC, zv);
            h2v dD = __builtin_elementwise_max(sD[t] - hpD, zv);
            aC0 += __builtin_amdgcn_sqrtf((float)dC[0]);
            aC1 += __builtin_amdgcn_sqrtf((float)dC[1]);
            aD0 += __builtin_amdgcn_sqrtf((float)dD[0]);
            aD1 += __builtin_amdgcn_sqrtf((float)dD[1]);
        }
        if (dmCD > 12) {
#pragma unroll
            for (int t = 0; t < 4; t++) {
                int eC = __builtin_amdgcn_readlane(e_sel, 44 + t);
                int eD = __builtin_amdgcn_readlane(e_sel, 60 + t);
                __half2 hv;
                h2v uC, uD;
                hv = S[(size_t)eC * 64 + lane]; __builtin_memcpy(&uC, &hv, 4);
                hv = S[(size_t)eD * 64 + lane]; __builtin_memcpy(&uD, &hv, 4);
                h2v dC = __builtin_elementwise_max(uC - hpC, zv);
                h2v dD = __builtin_elementwise_max(uD - hpD, zv);
                aC0 += __builtin_amdgcn_sqrtf((float)dC[0]);
                aC1 += __builtin_amdgcn_sqrtf((float)dC[1]);
                aD0 += __builtin_amdgcn_sqrtf((float)dD[0]);
                aD1 += __builtin_amdgcn_sqrtf((float)dD[1]);
            }
        }
    }

    // rare tails deg > 16 (P ~ 0.4%/node)
    if (dmax > 16) {
        float hA0 = (float)hpA[0], hA1 = (float)hpA[1];
        float hB0 = (float)hpB[0], hB1 = (float)hpB[1];
        float hC0 = (float)hpC[0], hC1 = (float)hpC[1];
        float hD0 = (float)hpD[0], hD1 = (float)hpD[1];
        for (int t = 16; t < dgA; t++) {
            int e = lst[(n0 + 0) * CAP + t];
            __half2 sh = S[(size_t)e * 64 + lane];
            aA0 += __builtin_amdgcn_sqrtf(fmaxf(__low2float(sh)  - hA0, 0.0f));
            aA1 += __builtin_amdgcn_sqrtf(fmaxf(__high2float(sh) - hA1, 0.0f));
        }
        for (int t = 16; t < dgB; t++) {
            int e = lst[(n0 + 1) * CAP + t];
            __half2 sh = S[(size_t)e * 64 + lane];
            aB0 += __builtin_amdgcn_sqrtf(fmaxf(__low2float(sh)  - hB0, 0.0f));
            aB1 += __builtin_amdgcn_sqrtf(fmaxf(__high2float(sh) - hB1, 0.0f));
        }
        for (int t = 16; t < dgC; t++) {
            int e = lst[(n0 + 2) * CAP + t];
            __half2 sh = S[(size_t)e * 64 + lane];
            aC0 += __builtin_amdgcn_sqrtf(fmaxf(__low2float(sh)  - hC0, 0.0f));
            aC1 += __builtin_amdgcn_sqrtf(fmaxf(__high2float(sh) - hC1, 0.0f));
        }
        for (int t = 16; t < dgD; t++) {
            int e = lst[(n0 + 3) * CAP + t];
            __half2 sh = S[(size_t)e * 64 + lane];
            aD0 += __builtin_amdgcn_sqrtf(fmaxf(__low2float(sh)  - hD0, 0.0f));
            aD1 += __builtin_amdgcn_sqrtf(fmaxf(__high2float(sh) - hD1, 0.0f));
        }
    }

    float nsA0 = __builtin_amdgcn_sqrtf((float)hpA[0]) + aA0 * SQRT_INV31;
    float nsA1 = __builtin_amdgcn_sqrtf((float)hpA[1]) + aA1 * SQRT_INV31;
    float nsB0 = __builtin_amdgcn_sqrtf((float)hpB[0]) + aB0 * SQRT_INV31;
    float nsB1 = __builtin_amdgcn_sqrtf((float)hpB[1]) + aB1 * SQRT_INV31;
    float nsC0 = __builtin_amdgcn_sqrtf((float)hpC[0]) + aC0 * SQRT_INV31;
    float nsC1 = __builtin_amdgcn_sqrtf((float)hpC[1]) + aC1 * SQRT_INV31;
    float nsD0 = __builtin_amdgcn_sqrtf((float)hpD[0]) + aD0 * SQRT_INV31;
    float nsD1 = __builtin_amdgcn_sqrtf((float)hpD[1]) + aD1 * SQRT_INV31;

    __shared__ float AHs[4][4][D1];             // wave-private [w][node][col]
    AHs[w][0][2 * lane] = nsA0;  AHs[w][0][2 * lane + 1] = nsA1;
    AHs[w][1][2 * lane] = nsB0;  AHs[w][1][2 * lane + 1] = nsB1;
    AHs[w][2][2 * lane] = nsC0;  AHs[w][2][2 * lane + 1] = nsC1;
    AHs[w][3][2 * lane] = nsD0;  AHs[w][3][2 * lane + 1] = nsD1;

    float vA = nsA0 + nsA1, vB = nsB0 + nsB1;
    float vC = nsC0 + nsC1, vD = nsD0 + nsD1;
#pragma unroll
    for (int m = 1; m < 64; m <<= 1) {
        vA += __shfl_xor(vA, m, 64);
        vB += __shfl_xor(vB, m, 64);
        vC += __shfl_xor(vC, m, 64);
        vD += __shfl_xor(vD, m, 64);
    }
    float rA = __builtin_amdgcn_rcpf(vA);
    float rB = __builtin_amdgcn_rcpf(vB);
    float rC = __builtin_amdgcn_rcpf(vC);
    float rD = __builtin_amdgcn_rcpf(vD);

    __threadfence_block();                      // LDS visibility within wave

    // ns[128] @ W1[128,16] for 4 nodes, sharing the W1t fragment.
    const float4* aAp = (const float4*)(&AHs[w][0][j * 32]);
    const float4* aBp = (const float4*)(&AHs[w][1][j * 32]);
    const float4* aCp = (const float4*)(&AHs[w][2][j * 32]);
    const float4* aDp = (const float4*)(&AHs[w][3][j * 32]);
    const float4* w1p = (const float4*)(W1t + c * D1 + j * 32);
    float pA = 0.0f, pB = 0.0f, pC = 0.0f, pD = 0.0f;
#pragma unroll
    for (int tt = 0; tt < 8; tt++) {
        float4 wv = w1p[tt];
        float4 xA = aAp[tt];
        float4 xB = aBp[tt];
        float4 xC = aCp[tt];
        float4 xD = aDp[tt];
        pA += xA.x * wv.x + xA.y * wv.y + xA.z * wv.z + xA.w * wv.w;
        pB += xB.x * wv.x + xB.y * wv.y + xB.z * wv.z + xB.w * wv.w;
        pC += xC.x * wv.x + xC.y * wv.y + xC.z * wv.z + xC.w * wv.w;
        pD += xD.x * wv.x + xD.y * wv.y + xD.z * wv.z + xD.w * wv.w;
    }
    pA += __shfl_xor(pA, 16, 64);  pA += __shfl_xor(pA, 32, 64);
    pB += __shfl_xor(pB, 16, 64);  pB += __shfl_xor(pB, 32, 64);
    pC += __shfl_xor(pC, 16, 64);  pC += __shfl_xor(pC, 32, 64);
    pD += __shfl_xor(pD, 16, 64);  pD += __shfl_xor(pD, 32, 64);

    float bb = b1[c];
    float oA = fminf(fmaxf(bb + pA * rA, CLAMP_LO), CLAMP_HI);
    float oB = fminf(fmaxf(bb + pB * rB, CLAMP_LO), CLAMP_HI);
    float oC = fminf(fmaxf(bb + pC * rC, CLAMP_LO), CLAMP_HI);
    float oD = fminf(fmaxf(bb + pD * rD, CLAMP_LO), CLAMP_HI);
    float qA = oA * oA, qB = oB * oB, qC = oC * oC, qD = oD * oD;
    // lane g*16+c stores node n0+g, col c  ->  Hp2 + 64*quad + lane (coalesced)
    float val = (g == 0) ? qA : (g == 1) ? qB : (g == 2) ? qC : qD;
    Hp2[(size_t)quad * 64 + lane] = val;
}

// S2[e,:] = sum over 32 nodes of Hp2[node,:] (d=16, fp32).
__global__ __launch_bounds__(256) void k_edge_sum2(const float* __restrict__ Hp2,
                                                   const int* __restrict__ idx,
                                                   float* __restrict__ S2, int E) {
    int e = blockIdx.x * 16 + (threadIdx.x >> 4);
    int col = threadIdx.x & 15;
    if (e >= E) return;
    float acc = 0.0f;
#pragma unroll
    for (int j = 0; j < K_EDGE; j++) {
        int n = idx[e * K_EDGE + j];
        acc += Hp2[(size_t)n * D2 + col];
    }
    S2[(size_t)e * D2 + col] = acc;
}

// Fused layer-2 node kernel, quad structure (mirrors k_node1): FOUR nodes
// per wave, lane -> (g=lane>>4 node, col=lane&15). Coalesced lst + Hp2
// loads; 12 unconditional S2 gathers per lane (zero-row padding; S2 is
// L2-resident so padding gathers are ~free); compute gated 8+4+4 on quad
// max-degree (slots/node 16 -> ~13.2); per-wave fixed costs (deg load,
// reduction, W2 MAC loop) amortized over 4 nodes instead of 2.
__global__ __launch_bounds__(256) void k_node2(const float* __restrict__ Hp2,
                                               const float* __restrict__ S2,
                                               const int* __restrict__ deg,
                                               const ushort_t* __restrict__ lst,
                                               const float* __restrict__ W2,
                                               const float* __restrict__ b2,
                                               float* __restrict__ out, int N, int E) {
    int w = threadIdx.x >> 6;
    int lane = threadIdx.x & 63;
    int quad = blockIdx.x * 4 + w;              // wave handles nodes 4q..4q+3
    int n0 = quad * 4;                          // N % 16 == 0
    int col = lane & 15;
    int g = lane >> 4;
    int nn = n0 + g;

    int4 d4 = ((const int4*)deg)[quad];
    int dgA = min(d4.x, CAP), dgB = min(d4.y, CAP);
    int dgC = min(d4.z, CAP), dgD = min(d4.w, CAP);
    int dsel = (g == 0) ? dgA : (g == 1) ? dgB : (g == 2) ? dgC : dgD;

    ushort_t idu = lst[(size_t)nn * CAP + col];        // slot col of node g
    int e_sel = (col < dsel) ? (int)idu : E;           // E = zero row of S2

    float hp = Hp2[(size_t)n0 * D2 + lane];            // coalesced 256B/wave
    int dmax = max(max(dgA, dgB), max(dgC, dgD));

    // unconditional: slots 0..11 of own node (ev via bpermute-shfl)
    int ev[12];
#pragma unroll
    for (int t = 0; t < 12; t++) ev[t] = __shfl(e_sel, g * 16 + t, 64);
    float sv[12];
#pragma unroll
    for (int t = 0; t < 12; t++) sv[t] = S2[(size_t)ev[t] * D2 + col];

    float acc = 0.0f;
#pragma unroll
    for (int t = 0; t < 8; t++)
        acc += __builtin_amdgcn_sqrtf(fmaxf(sv[t] - hp, 0.0f));
    if (dmax > 8) {
#pragma unroll
        for (int t = 8; t < 12; t++)
            acc += __builtin_amdgcn_sqrtf(fmaxf(sv[t] - hp, 0.0f));
        if (dmax > 12) {
#pragma unroll
            for (int t = 12; t < 16; t++) {
                int e = __shfl(e_sel, g * 16 + t, 64);
                float s = S2[(size_t)e * D2 + col];
                acc += __builtin_amdgcn_sqrtf(fmaxf(s - hp, 0.0f));
            }
        }
    }
    if (dmax > 16) {                            // rare tails (P ~ 0.4%/node)
        for (int t = 16; t < dsel; t++) {
            int e = lst[(size_t)nn * CAP + t];  // broadcast within group
            float s = S2[(size_t)e * D2 + col];
            acc += __builtin_amdgcn_sqrtf(fmaxf(s - hp, 0.0f));
        }
    }
    float ns = __builtin_amdgcn_sqrtf(hp) + acc * SQRT_INV31;

    // rowsum over the 16 cols within each 16-lane group
    float v = ns;
#pragma unroll
    for (int m = 1; m < 16; m <<= 1) v += __shfl_xor(v, m, 64);
    float r = __builtin_amdgcn_rcpf(v);

    __shared__ float AHs[4][4][D2];             // wave-private [w][node][col]
    AHs[w][g][col] = ns * r;
    __threadfence_block();

    if (lane < C_OUT) {
        float o0 = b2[lane], o1 = o0, o2 = o0, o3 = o0;
#pragma unroll
        for (int i = 0; i < D2; i++) {
            float wv = W2[i * C_OUT + lane];
            o0 += AHs[w][0][i] * wv;
            o1 += AHs[w][1][i] * wv;
            o2 += AHs[w][2][i] * wv;
            o3 += AHs[w][3][i] * wv;
        }
        out[(size_t)(n0 + 0) * C_OUT + lane] = o0;
        out[(size_t)(n0 + 1) * C_OUT + lane] = o1;
        out[(size_t)(n0 + 2) * C_OUT + lane] = o2;
        out[(size_t)(n0 + 3) * C_OUT + lane] = o3;
    }
}

extern "C" void kernel_launch(void* const* d_in, const int* in_sizes, int n_in,
                              void* d_out, int out_size, void* d_ws, size_t ws_size,
                              hipStream_t stream) {
    const float* x   = (const float*)d_in[0];
    const int*   idx = (const int*)d_in[1];
    const float* W1  = (const float*)d_in[2];
    const float* b1  = (const float*)d_in[3];
    const float* W2  = (const float*)d_in[4];
    const float* b2  = (const float*)d_in[5];
    float* out = (float*)d_out;

    int N = in_sizes[0] / D1;     // 100000
    int E = in_sizes[1] / K_EDGE; // 25000

    // workspace layout (S and S2 have one extra zero row at index E)
    __half2* Hp = (__half2*)d_ws;                          // N*64 half2
    __half2* S  = Hp + (size_t)N * 64;                     // (E+1)*64 half2
    float* Hp2  = (float*)(S + (size_t)(E + 1) * 64);      // N*16 fp32
    float* S2   = Hp2 + (size_t)N * D2;                    // (E+1)*16 fp32
    float* W1t  = S2 + (size_t)(E + 1) * D2;               // 16*128 fp32
    int*   deg  = (int*)(W1t + D1 * D2);                   // N ints
    ushort_t* lst = (ushort_t*)(deg + N);                  // N*CAP uint16

    int n4 = N * D1 / 4;           // 3200000

    (void)hipMemsetAsync(deg, 0, (size_t)N * sizeof(int), stream);
    k_setup<<<(n4 + 255) / 256, 256, 0, stream>>>(x, Hp, W1, W1t, S, S2, n4, E);
    k_edge_sum<<<E / 8, 256, 0, stream>>>(Hp, idx, S, deg, lst, E);
    k_node1<<<N / 16, 256, 0, stream>>>(Hp, S, deg, lst, W1t, b1, Hp2, N, E);
    k_edge_sum2<<<(E + 15) / 16, 256, 0, stream>>>(Hp2, idx, S2, E);
    k_node2<<<N / 16, 256, 0, stream>>>(Hp2, S2, deg, lst, W2, b2, out, N, E);
}

// Round 11
// 213.305 us; speedup vs baseline: 1.0595x; 1.0266x over previous
//
#include <hip/hip_runtime.h>
#include <hip/hip_fp16.h>
#include <math.h>

#define CAP 64          // max incidences per node (mean deg = 8)
#define D1 128
#define D2 16
#define C_OUT 40
#define K_EDGE 32
#define CLAMP_LO 1e-7f
#define CLAMP_HI 10.0f
#define SQRT_INV31 0.1796053020267749f   // sqrt(1/31)

typedef unsigned short ushort_t;
typedef _Float16 h2v __attribute__((ext_vector_type(2)));   // packed fp16 pair

// Pure-streaming setup: clip+square -> Hp (fp16), W1 transpose, zero rows of
// S/S2, and deg zeroing (folded in; removes the separate memset dispatch).
__global__ __launch_bounds__(256) void k_setup(const float* __restrict__ x,
                                               __half2* __restrict__ Hp,
                                               const float* __restrict__ W1,
                                               float* __restrict__ W1t,
                                               __half2* __restrict__ S,
                                               float* __restrict__ S2,
                                               int* __restrict__ deg,
                                               int n4, int N, int E) {
    int i = blockIdx.x * 256 + threadIdx.x;
    if (i < n4) {                                  // clip + square, 4 floats
        float4 v = ((const float4*)x)[i];
        v.x = fminf(fmaxf(v.x, CLAMP_LO), CLAMP_HI);
        v.y = fminf(fmaxf(v.y, CLAMP_LO), CLAMP_HI);
        v.z = fminf(fmaxf(v.z, CLAMP_LO), CLAMP_HI);
        v.w = fminf(fmaxf(v.w, CLAMP_LO), CLAMP_HI);
        __half2 h0 = __floats2half2_rn(v.x * v.x, v.y * v.y);
        __half2 h1 = __floats2half2_rn(v.z * v.z, v.w * v.w);
        uint2 st;
        __builtin_memcpy(&st.x, &h0, 4);
        __builtin_memcpy(&st.y, &h1, 4);
        ((uint2*)Hp)[i] = st;                      // one 8B store
    }
    if (i < N) deg[i] = 0;                         // was hipMemsetAsync
    if (i < D1 * D2) W1t[(i & 15) * D1 + (i >> 4)] = W1[i];
    if (i < 64) S[(size_t)E * 64 + i] = __floats2half2_rn(0.0f, 0.0f);
    if (i < D2) S2[(size_t)E * D2 + i] = 0.0f;
}

// S[e,:] = sum of Hp[node,:] over the edge's 32 nodes + fused incidence
// build (r7 2-edge version; r8/r9 showed the kernel is L2-path-throughput
// bound (~3 TB/s combined, FETCH 92MB = XCD-duplicated Hp, WRITE 55MB =
// lst 2B-scatter line RMW) and insensitive to per-wave MLP. Left alone.
__global__ __launch_bounds__(256) void k_edge_sum(const __half2* __restrict__ Hp,
                                                  const int* __restrict__ idx,
                                                  __half2* __restrict__ S,
                                                  int* __restrict__ deg,
                                                  ushort_t* __restrict__ lst, int E) {
    int w = threadIdx.x >> 6;
    int lane = threadIdx.x & 63;
    int eA = blockIdx.x * 8 + w * 2;            // E % 8 == 0
    int nid = idx[eA * K_EDGE + lane];          // 32 ids of eA + 32 ids of eA+1
    float a0 = 0.0f, a1 = 0.0f, b0 = 0.0f, b1 = 0.0f;
#pragma unroll
    for (int j = 0; j < K_EDGE; j++) {
        int nA = __builtin_amdgcn_readlane(nid, j);
        int nB = __builtin_amdgcn_readlane(nid, 32 + j);
        __half2 hA = Hp[(size_t)nA * 64 + lane];
        __half2 hB = Hp[(size_t)nB * 64 + lane];
        a0 += __low2float(hA); a1 += __high2float(hA);
        b0 += __low2float(hB); b1 += __high2float(hB);
    }
    // incidence build for the 64 incidences this wave already loaded
    int e_of = eA + (lane >> 5);                // lane<32 -> eA, else eA+1
    int pos = atomicAdd(&deg[nid], 1);
    if (pos < CAP) lst[(size_t)nid * CAP + pos] = (ushort_t)e_of;

    S[(size_t)eA * 64 + lane]       = __floats2half2_rn(a0, a1);
    S[(size_t)(eA + 1) * 64 + lane] = __floats2half2_rn(b0, b1);
}

// 4-slot fp16 partial: p = sum of sqrt_f16(max(s[t]-hp,0)), t in [base,base+4)
// 23 VALU ops per 4 slots vs 32 for the f32-sqrt path (~28% hot-loop cut).
// fp16 partial spans only 4 values -> rounding error ~2^-11 rel, negligible
// after *SQRT_INV31 and row-normalization.
#define SQ4(p, s, base, hp)                                                   \
    {                                                                         \
        h2v d0_ = __builtin_elementwise_max((s)[(base) + 0] - (hp), zv);      \
        h2v d1_ = __builtin_elementwise_max((s)[(base) + 1] - (hp), zv);      \
        h2v d2_ = __builtin_elementwise_max((s)[(base) + 2] - (hp), zv);      \
        h2v d3_ = __builtin_elementwise_max((s)[(base) + 3] - (hp), zv);      \
        p = __builtin_elementwise_sqrt(d0_) + __builtin_elementwise_sqrt(d1_) \
          + __builtin_elementwise_sqrt(d2_) + __builtin_elementwise_sqrt(d3_);\
    }

// Fused layer-1 node kernel. FOUR nodes per wave; gathers for slots 0..11
// unconditional (latency-hidden; padding hits zero row E). Slot COMPUTE is
// gated per node-PAIR (AB / CD) on the pair max-degree. Inner math: fp16
// sqrt + 4-slot fp16 partial sums, fp32 master accumulators.
__global__ __launch_bounds__(256) void k_node1(const __half2* __restrict__ Hp,
                                               const __half2* __restrict__ S,
                                               const int* __restrict__ deg,
                                               const ushort_t* __restrict__ lst,
                                               const float* __restrict__ W1t,
                                               const float* __restrict__ b1,
                                               float* __restrict__ Hp2, int N, int E) {
    int w = threadIdx.x >> 6;
    int lane = threadIdx.x & 63;
    int quad = blockIdx.x * 4 + w;              // wave handles nodes 4q..4q+3
    int n0 = quad * 4;                          // N % 16 == 0
    int c = lane & 15, j = lane >> 4;
    int sl = lane & 15, g = lane >> 4;

    int4 d4 = ((const int4*)deg)[quad];
    int dgA = min(d4.x, CAP), dgB = min(d4.y, CAP);
    int dgC = min(d4.z, CAP), dgD = min(d4.w, CAP);

    // coalesced: lane g*16+sl loads slot sl of node n0+g
    ushort_t idu = lst[(n0 + g) * CAP + sl];
    int dsel = (g == 0) ? dgA : (g == 1) ? dgB : (g == 2) ? dgC : dgD;
    int e_sel = (sl < dsel) ? (int)idu : E;

    __half2 hphA = Hp[(size_t)(n0 + 0) * 64 + lane];
    __half2 hphB = Hp[(size_t)(n0 + 1) * 64 + lane];
    __half2 hphC = Hp[(size_t)(n0 + 2) * 64 + lane];
    __half2 hphD = Hp[(size_t)(n0 + 3) * 64 + lane];
    h2v hpA, hpB, hpC, hpD;
    __builtin_memcpy(&hpA, &hphA, 4);
    __builtin_memcpy(&hpB, &hphB, 4);
    __builtin_memcpy(&hpC, &hphC, 4);
    __builtin_memcpy(&hpD, &hphD, 4);
    const h2v zv = (h2v)(_Float16)0.0f;

    int dmAB = max(dgA, dgB);
    int dmCD = max(dgC, dgD);
    int dmax = max(dmAB, dmCD);

    float aA0 = 0.0f, aA1 = 0.0f, aB0 = 0.0f, aB1 = 0.0f;
    float aC0 = 0.0f, aC1 = 0.0f, aD0 = 0.0f, aD1 = 0.0f;

    // ---- unconditional prefetch: slots 0..11 x 4 nodes (48 gathers) ----
    h2v sA[12], sB[12], sC[12], sD[12];
#pragma unroll
    for (int t = 0; t < 12; t++) {
        int eA = __builtin_amdgcn_readlane(e_sel, t);
        int eB = __builtin_amdgcn_readlane(e_sel, 16 + t);
        int eC = __builtin_amdgcn_readlane(e_sel, 32 + t);
        int eD = __builtin_amdgcn_readlane(e_sel, 48 + t);
        __half2 hv;
        hv = S[(size_t)eA * 64 + lane]; __builtin_memcpy(&sA[t], &hv, 4);
        hv = S[(size_t)eB * 64 + lane]; __builtin_memcpy(&sB[t], &hv, 4);
        hv = S[(size_t)eC * 64 + lane]; __builtin_memcpy(&sC[t], &hv, 4);
        hv = S[(size_t)eD * 64 + lane]; __builtin_memcpy(&sD[t], &hv, 4);
    }

    // ---- compute slots 0..7 (covers deg <= 8): two 4-slot fp16 groups ----
    {
        h2v pA, pB, pC, pD;
        SQ4(pA, sA, 0, hpA);  SQ4(pB, sB, 0, hpB);
        SQ4(pC, sC, 0, hpC);  SQ4(pD, sD, 0, hpD);
        h2v qA, qB, qC, qD;
        SQ4(qA, sA, 4, hpA);  SQ4(qB, sB, 4, hpB);
        SQ4(qC, sC, 4, hpC);  SQ4(qD, sD, 4, hpD);
        aA0 += (float)pA[0] + (float)qA[0];  aA1 += (float)pA[1] + (float)qA[1];
        aB0 += (float)pB[0] + (float)qB[0];  aB1 += (float)pB[1] + (float)qB[1];
        aC0 += (float)pC[0] + (float)qC[0];  aC1 += (float)pC[1] + (float)qC[1];
        aD0 += (float)pD[0] + (float)qD[0];  aD1 += (float)pD[1] + (float)qD[1];
    }

    // ---- pair AB: slots 8..11 (P~0.70), 12..15 (P~0.12) ----
    if (dmAB > 8) {
        h2v pA, pB;
        SQ4(pA, sA, 8, hpA);  SQ4(pB, sB, 8, hpB);
        aA0 += (float)pA[0];  aA1 += (float)pA[1];
        aB0 += (float)pB[0];  aB1 += (float)pB[1];
        if (dmAB > 12) {
            h2v uA[4], uB[4];
#pragma unroll
            for (int t = 0; t < 4; t++) {
                int eA = __builtin_amdgcn_readlane(e_sel, 12 + t);
                int eB = __builtin_amdgcn_readlane(e_sel, 28 + t);
                __half2 hv;
                hv = S[(size_t)eA * 64 + lane]; __builtin_memcpy(&uA[t], &hv, 4);
                hv = S[(size_t)eB * 64 + lane]; __builtin_memcpy(&uB[t], &hv, 4);
            }
            h2v vA, vB;
            SQ4(vA, uA, 0, hpA);  SQ4(vB, uB, 0, hpB);
            aA0 += (float)vA[0];  aA1 += (float)vA[1];
            aB0 += (float)vB[0];  aB1 += (float)vB[1];
        }
    }

    // ---- pair CD: slots 8..11, 12..15 ----
    if (dmCD > 8) {
        h2v pC, pD;
        SQ4(pC, sC, 8, hpC);  SQ4(pD, sD, 8, hpD);
        aC0 += (float)pC[0];  aC1 += (float)pC[1];
        aD0 += (float)pD[0];  aD1 += (float)pD[1];
        if (dmCD > 12) {
            h2v uC[4], uD[4];
#pragma unroll
            for (int t = 0; t < 4; t++) {
                int eC = __builtin_amdgcn_readlane(e_sel, 44 + t);
                int eD = __builtin_amdgcn_readlane(e_sel, 60 + t);
                __half2 hv;
                hv = S[(size_t)eC * 64 + lane]; __builtin_memcpy(&uC[t], &hv, 4);
                hv = S[(size_t)eD * 64 + lane]; __builtin_memcpy(&uD[t], &hv, 4);
            }
            h2v vC, vD;
            SQ4(vC, uC, 0, hpC);  SQ4(vD, uD, 0, hpD);
            aC0 += (float)vC[0];  aC1 += (float)vC[1];
            aD0 += (float)vD[0];  aD1 += (float)vD[1];
        }
    }

    // rare tails deg > 16 (P ~ 0.4%/node) — f32 path, cold
    if (dmax > 16) {
        float hA0 = (float)hpA[0], hA1 = (float)hpA[1];
        float hB0 = (float)hpB[0], hB1 = (float)hpB[1];
        float hC0 = (float)hpC[0], hC1 = (float)hpC[1];
        float hD0 = (float)hpD[0], hD1 = (float)hpD[1];
        for (int t = 16; t < dgA; t++) {
            int e = lst[(n0 + 0) * CAP + t];
            __half2 sh = S[(size_t)e * 64 + lane];
            aA0 += __builtin_amdgcn_sqrtf(fmaxf(__low2float(sh)  - hA0, 0.0f));
            aA1 += __builtin_amdgcn_sqrtf(fmaxf(__high2float(sh) - hA1, 0.0f));
        }
        for (int t = 16; t < dgB; t++) {
            int e = lst[(n0 + 1) * CAP + t];
            __half2 sh = S[(size_t)e * 64 + lane];
            aB0 += __builtin_amdgcn_sqrtf(fmaxf(__low2float(sh)  - hB0, 0.0f));
            aB1 += __builtin_amdgcn_sqrtf(fmaxf(__high2float(sh) - hB1, 0.0f));
        }
        for (int t = 16; t < dgC; t++) {
            int e = lst[(n0 + 2) * CAP + t];
            __half2 sh = S[(size_t)e * 64 + lane];
            aC0 += __builtin_amdgcn_sqrtf(fmaxf(__low2float(sh)  - hC0, 0.0f));
            aC1 += __builtin_amdgcn_sqrtf(fmaxf(__high2float(sh) - hC1, 0.0f));
        }
        for (int t = 16; t < dgD; t++) {
            int e = lst[(n0 + 3) * CAP + t];
            __half2 sh = S[(size_t)e * 64 + lane];
            aD0 += __builtin_amdgcn_sqrtf(fmaxf(__low2float(sh)  - hD0, 0.0f));
            aD1 += __builtin_amdgcn_sqrtf(fmaxf(__high2float(sh) - hD1, 0.0f));
        }
    }

    float nsA0 = __builtin_amdgcn_sqrtf((float)hpA[0]) + aA0 * SQRT_INV31;
    float nsA1 = __builtin_amdgcn_sqrtf((float)hpA[1]) + aA1 * SQRT_INV31;
    float nsB0 = __builtin_amdgcn_sqrtf((float)hpB[0]) + aB0 * SQRT_INV31;
    float nsB1 = __builtin_amdgcn_sqrtf((float)hpB[1]) + aB1 * SQRT_INV31;
    float nsC0 = __builtin_amdgcn_sqrtf((float)hpC[0]) + aC0 * SQRT_INV31;
    float nsC1 = __builtin_amdgcn_sqrtf((float)hpC[1]) + aC1 * SQRT_INV31;
    float nsD0 = __builtin_amdgcn_sqrtf((float)hpD[0]) + aD0 * SQRT_INV31;
    float nsD1 = __builtin_amdgcn_sqrtf((float)hpD[1]) + aD1 * SQRT_INV31;

    __shared__ float AHs[4][4][D1];             // wave-private [w][node][col]
    AHs[w][0][2 * lane] = nsA0;  AHs[w][0][2 * lane + 1] = nsA1;
    AHs[w][1][2 * lane] = nsB0;  AHs[w][1][2 * lane + 1] = nsB1;
    AHs[w][2][2 * lane] = nsC0;  AHs[w][2][2 * lane + 1] = nsC1;
    AHs[w][3][2 * lane] = nsD0;  AHs[w][3][2 * lane + 1] = nsD1;

    float vA = nsA0 + nsA1, vB = nsB0 + nsB1;
    float vC = nsC0 + nsC1, vD = nsD0 + nsD1;
#pragma unroll
    for (int m = 1; m < 64; m <<= 1) {
        vA += __shfl_xor(vA, m, 64);
        vB += __shfl_xor(vB, m, 64);
        vC += __shfl_xor(vC, m, 64);
        vD += __shfl_xor(vD, m, 64);
    }
    float rA = __builtin_amdgcn_rcpf(vA);
    float rB = __builtin_amdgcn_rcpf(vB);
    float rC = __builtin_amdgcn_rcpf(vC);
    float rD = __builtin_amdgcn_rcpf(vD);

    __threadfence_block();                      // LDS visibility within wave

    // ns[128] @ W1[128,16] for 4 nodes, sharing the W1t fragment.
    const float4* aAp = (const float4*)(&AHs[w][0][j * 32]);
    const float4* aBp = (const float4*)(&AHs[w][1][j * 32]);
    const float4* aCp = (const float4*)(&AHs[w][2][j * 32]);
    const float4* aDp = (const float4*)(&AHs[w][3][j * 32]);
    const float4* w1p = (const float4*)(W1t + c * D1 + j * 32);
    float pA = 0.0f, pB = 0.0f, pC = 0.0f, pD = 0.0f;
#pragma unroll
    for (int tt = 0; tt < 8; tt++) {
        float4 wv = w1p[tt];
        float4 xA = aAp[tt];
        float4 xB = aBp[tt];
        float4 xC = aCp[tt];
        float4 xD = aDp[tt];
        pA += xA.x * wv.x + xA.y * wv.y + xA.z * wv.z + xA.w * wv.w;
        pB += xB.x * wv.x + xB.y * wv.y + xB.z * wv.z + xB.w * wv.w;
        pC += xC.x * wv.x + xC.y * wv.y + xC.z * wv.z + xC.w * wv.w;
        pD += xD.x * wv.x + xD.y * wv.y + xD.z * wv.z + xD.w * wv.w;
    }
    pA += __shfl_xor(pA, 16, 64);  pA += __shfl_xor(pA, 32, 64);
    pB += __shfl_xor(pB, 16, 64);  pB += __shfl_xor(pB, 32, 64);
    pC += __shfl_xor(pC, 16, 64);  pC += __shfl_xor(pC, 32, 64);
    pD += __shfl_xor(pD, 16, 64);  pD += __shfl_xor(pD, 32, 64);

    float bb = b1[c];
    float oA = fminf(fmaxf(bb + pA * rA, CLAMP_LO), CLAMP_HI);
    float oB = fminf(fmaxf(bb + pB * rB, CLAMP_LO), CLAMP_HI);
    float oC = fminf(fmaxf(bb + pC * rC, CLAMP_LO), CLAMP_HI);
    float oD = fminf(fmaxf(bb + pD * rD, CLAMP_LO), CLAMP_HI);
    float qA = oA * oA, qB = oB * oB, qC = oC * oC, qD = oD * oD;
    // lane g*16+c stores node n0+g, col c  ->  Hp2 + 64*quad + lane (coalesced)
    float val = (g == 0) ? qA : (g == 1) ? qB : (g == 2) ? qC : qD;
    Hp2[(size_t)quad * 64 + lane] = val;
}

// S2[e,:] = sum over 32 nodes of Hp2[node,:] (d=16, fp32).
__global__ __launch_bounds__(256) void k_edge_sum2(const float* __restrict__ Hp2,
                                                   const int* __restrict__ idx,
                                                   float* __restrict__ S2, int E) {
    int e = blockIdx.x * 16 + (threadIdx.x >> 4);
    int col = threadIdx.x & 15;
    if (e >= E) return;
    float acc = 0.0f;
#pragma unroll
    for (int j = 0; j < K_EDGE; j++) {
        int n = idx[e * K_EDGE + j];
        acc += Hp2[(size_t)n * D2 + col];
    }
    S2[(size_t)e * D2 + col] = acc;
}

// Fused layer-2 node kernel, quad structure: FOUR nodes per wave,
// lane -> (g=lane>>4 node, col=lane&15). 12 unconditional S2 gathers
// (zero-row padding; S2 L2-resident); compute gated 8+4+4 on quad max.
__global__ __launch_bounds__(256) void k_node2(const float* __restrict__ Hp2,
                                               const float* __restrict__ S2,
                                               const int* __restrict__ deg,
                                               const ushort_t* __restrict__ lst,
                                               const float* __restrict__ W2,
                                               const float* __restrict__ b2,
                                               float* __restrict__ out, int N, int E) {
    int w = threadIdx.x >> 6;
    int lane = threadIdx.x & 63;
    int quad = blockIdx.x * 4 + w;              // wave handles nodes 4q..4q+3
    int n0 = quad * 4;                          // N % 16 == 0
    int col = lane & 15;
    int g = lane >> 4;
    int nn = n0 + g;

    int4 d4 = ((const int4*)deg)[quad];
    int dgA = min(d4.x, CAP), dgB = min(d4.y, CAP);
    int dgC = min(d4.z, CAP), dgD = min(d4.w, CAP);
    int dsel = (g == 0) ? dgA : (g == 1) ? dgB : (g == 2) ? dgC : dgD;

    ushort_t idu = lst[(size_t)nn * CAP + col];        // slot col of node g
    int e_sel = (col < dsel) ? (int)idu : E;           // E = zero row of S2

    float hp = Hp2[(size_t)n0 * D2 + lane];            // coalesced 256B/wave
    int dmax = max(max(dgA, dgB), max(dgC, dgD));

    // unconditional: slots 0..11 of own node
    int ev[12];
#pragma unroll
    for (int t = 0; t < 12; t++) ev[t] = __shfl(e_sel, g * 16 + t, 64);
    float sv[12];
#pragma unroll
    for (int t = 0; t < 12; t++) sv[t] = S2[(size_t)ev[t] * D2 + col];

    float acc = 0.0f;
#pragma unroll
    for (int t = 0; t < 8; t++)
        acc += __builtin_amdgcn_sqrtf(fmaxf(sv[t] - hp, 0.0f));
    if (dmax > 8) {
#pragma unroll
        for (int t = 8; t < 12; t++)
            acc += __builtin_amdgcn_sqrtf(fmaxf(sv[t] - hp, 0.0f));
        if (dmax > 12) {
#pragma unroll
            for (int t = 12; t < 16; t++) {
                int e = __shfl(e_sel, g * 16 + t, 64);
                float s = S2[(size_t)e * D2 + col];
                acc += __builtin_amdgcn_sqrtf(fmaxf(s - hp, 0.0f));
            }
        }
    }
    if (dmax > 16) {                            // rare tails (P ~ 0.4%/node)
        for (int t = 16; t < dsel; t++) {
            int e = lst[(size_t)nn * CAP + t];  // broadcast within group
            float s = S2[(size_t)e * D2 + col];
            acc += __builtin_amdgcn_sqrtf(fmaxf(s - hp, 0.0f));
        }
    }
    float ns = __builtin_amdgcn_sqrtf(hp) + acc * SQRT_INV31;

    // rowsum over the 16 cols within each 16-lane group
    float v = ns;
#pragma unroll
    for (int m = 1; m < 16; m <<= 1) v += __shfl_xor(v, m, 64);
    float r = __builtin_amdgcn_rcpf(v);

    __shared__ float AHs[4][4][D2];             // wave-private [w][node][col]
    AHs[w][g][col] = ns * r;
    __threadfence_block();

    if (lane < C_OUT) {
        float o0 = b2[lane], o1 = o0, o2 = o0, o3 = o0;
#pragma unroll
        for (int i = 0; i < D2; i++) {
            float wv = W2[i * C_OUT + lane];
            o0 += AHs[w][0][i] * wv;
            o1 += AHs[w][1][i] * wv;
            o2 += AHs[w][2][i] * wv;
            o3 += AHs[w][3][i] * wv;
        }
        out[(size_t)(n0 + 0) * C_OUT + lane] = o0;
        out[(size_t)(n0 + 1) * C_OUT + lane] = o1;
        out[(size_t)(n0 + 2) * C_OUT + lane] = o2;
        out[(size_t)(n0 + 3) * C_OUT + lane] = o3;
    }
}

extern "C" void kernel_launch(void* const* d_in, const int* in_sizes, int n_in,
                              void* d_out, int out_size, void* d_ws, size_t ws_size,
                              hipStream_t stream) {
    const float* x   = (const float*)d_in[0];
    const int*   idx = (const int*)d_in[1];
    const float* W1  = (const float*)d_in[2];
    const float* b1  = (const float*)d_in[3];
    const float* W2  = (const float*)d_in[4];
    const float* b2  = (const float*)d_in[5];
    float* out = (float*)d_out;

    int N = in_sizes[0] / D1;     // 100000
    int E = in_sizes[1] / K_EDGE; // 25000

    // workspace layout (S and S2 have one extra zero row at index E)
    __half2* Hp = (__half2*)d_ws;                          // N*64 half2
    __half2* S  = Hp + (size_t)N * 64;                     // (E+1)*64 half2
    float* Hp2  = (float*)(S + (size_t)(E + 1) * 64);      // N*16 fp32
    float* S2   = Hp2 + (size_t)N * D2;                    // (E+1)*16 fp32
    float* W1t  = S2 + (size_t)(E + 1) * D2;               // 16*128 fp32
    int*   deg  = (int*)(W1t + D1 * D2);                   // N ints
    ushort_t* lst = (ushort_t*)(deg + N);                  // N*CAP uint16

    int n4 = N * D1 / 4;           // 3200000

    k_setup<<<(n4 + 255) / 256, 256, 0, stream>>>(x, Hp, W1, W1t, S, S2, deg,
                                                  n4, N, E);
    k_edge_sum<<<E / 8, 256, 0, stream>>>(Hp, idx, S, deg, lst, E);
    k_node1<<<N / 16, 256, 0, stream>>>(Hp, S, deg, lst, W1t, b1, Hp2, N, E);
    k_edge_sum2<<<(E + 15) / 16, 256, 0, stream>>>(Hp2, idx, S2, E);
    k_node2<<<N / 16, 256, 0, stream>>>(Hp2, S2, deg, lst, W2, b2, out, N, E);
}